// Round 7
// baseline (465.447 us; speedup 1.0000x reference)
//
#include <hip/hip_runtime.h>
#include <stdint.h>

// ---------------------------------------------------------------------------
// SchNetLayer on MI355X (gfx950).
// I/O: float tensors f32, indices int32. Internal: bf16 MFMA.
//
// R2: atomic scatter = atomic-rate bound -> counting sort.
// R3: libm softplus -> native v_exp/v_log.
// R4/R5: fuse gather/MLP/multiply/reduce into k_edge.
// R6-R8: LDS/occupancy tuning -> 128-edge tile, 3 blocks/CU, 159us.
// R9: lgkmcnt-only barriers: NEUTRAL (drains hidden by resident blocks).
// R10: 512thr+8-row strips: REGRESSED; flush count 1.5x -> time 1.33x.
// R11-R13: zacc v1: REGRESSED (29 barriers, quarter phases, idle waves,
//      + a rule-#20 acc spill in R11/R12 fixed by R13).
// R14: TILE=64, occupancy 52%: traffic identical to R8, VALUBusy still
//      ~35%, time 177us. 1.64x waves -> zero extra issue. DIAGNOSIS:
//      k_edge saturates GLOBAL ATOMIC RATE (~13.4M f32 atomics/dispatch,
//      ~84G/s; R10/R14 times track flush count, not occupancy/barriers).
// R15: kill the atomics, keep the R8 shape: 128-edge tile, 512 thr/8
//      waves, hc = all 128 rows (no halves -> every wave active in every
//      phase, 11 barriers/tile). Reduce flushes -> ds_add_f32 into
//      zacc[16][128]; per-n0 flush: interior receivers = plain float4
//      stores (sort-contiguity => exclusive), atomics only for the <=2
//      boundary slots + rare overflow. Global atomics 13.4M -> ~2.5M.
//      LDS 79.4KB -> 2 blocks/CU = 16 waves/CU (> R8's 12).
//
// Pipeline:
//   k_setup: z=0, cnt=0, weight transposes (one dispatch)
//   sort:  k_hist, k_scan, k_place        (counting sort by receiver)
//   k_he   : he = bf16(electrons) @ h_w   [8192,256] bf16   (64x64 tiles)
//   k_edge : per 128-edge tile: mid=SSP(dist[perm]@w1+b1); per n0:
//            we=mid@w2; stage 128 src rows; weh=we*src (own frags);
//            16-row-strip segmented reduce -> ds_add zacc; flush zacc->z
//   k_final: out = electrons + bf16(z) @ g_catT  f32 out   (64x64 tiles)
// ---------------------------------------------------------------------------

#define N_ELEC 8192
#define N_NUC  512
#define EMB    256
#define KER    256
#define DF     64
#define MID    128
#define NEDGE  131072
#define RPS    8256   // rowptr per-type stride (ints)
#define CSTR   272    // LDS row stride bytes for 128-col u16 tiles (+16 pad)
#define NSLOT  16     // zacc receiver slots per tile

using u16 = unsigned short;
using u64 = unsigned long long;
typedef short short8 __attribute__((ext_vector_type(8)));
typedef float f32x4 __attribute__((ext_vector_type(4)));

__device__ __forceinline__ float bf2f(u16 h) {
  return __uint_as_float(((unsigned)h) << 16);
}
__device__ __forceinline__ u16 f2bf(float f) {
  unsigned u = __float_as_uint(f);
  return (u16)((u + 0x7FFFu + ((u >> 16) & 1u)) >> 16);  // RNE
}
__device__ __forceinline__ unsigned pkbf(float a, float b) {
  return ((unsigned)f2bf(b) << 16) | (unsigned)f2bf(a);
}
// fast shifted softplus: log(0.5 e^x + 0.5), stable, native v_exp/v_log.
__device__ __forceinline__ float ssp_fast(float x) {
  const float e = __expf(-fabsf(x));
  return fmaxf(x, 0.f) + __logf(fmaf(0.5f, e, 0.5f));
}

// LDS-only workgroup barrier (R9): no vmcnt drain; all cross-wave deps in
// k_edge go through LDS (ds ops incl. ds_add are covered by lgkmcnt);
// global atomics stay fire-and-forget. sched_barrier(0) per rule #18.
__device__ __forceinline__ void bar_lds() {
  __builtin_amdgcn_sched_barrier(0);
  asm volatile("s_waitcnt lgkmcnt(0)" ::: "memory");
  __builtin_amdgcn_s_barrier();
  __builtin_amdgcn_sched_barrier(0);
}

// ---- 64x64 tile GEMM machinery (k_he / k_final) ----------------------------
__device__ __forceinline__ void stage_t64(const char* g0, long stride,
                                          char* lds, int tid) {
  const int l = tid & 63, w = tid >> 6;
  const int r = w * 16 + (l >> 2);
  const int cb = (l & 3) * 16;
  __builtin_amdgcn_global_load_lds(
      (const __attribute__((address_space(1))) unsigned*)(g0 +
                                                          (long)r * stride +
                                                          cb),
      (__attribute__((address_space(3))) unsigned*)(lds + w * 1024), 16, 0, 0);
}
__device__ __forceinline__ void stage_f64(const float* g0, int stride_e,
                                          int kt, char* lds, int tid) {
#pragma unroll
  for (int k = 0; k < 4; ++k) {
    const int idx2 = k * 256 + tid;
    const int row = idx2 >> 4, cp = idx2 & 15;
    const float2 v = *(const float2*)(g0 + (long)row * stride_e + kt + cp * 2);
    *(unsigned*)(lds + row * 64 + cp * 4) = pkbf(v.x, v.y);
  }
}
template <bool A_F32>
__device__ __forceinline__ void gemm64(const char* A0, long as_bytes,
                                       const float* Af, int as_elems,
                                       const char* B0, long bs, int K,
                                       char* As, char* Bs, f32x4 acc[2][2],
                                       int tid) {
  const int l = tid & 63, lane15 = l & 15, quad = l >> 4, wv = tid >> 6;
  const int mw = (wv >> 1) * 32, nw = (wv & 1) * 32;
  for (int kt = 0; kt < K; kt += 32) {
    if (A_F32)
      stage_f64(Af, as_elems, kt, As, tid);
    else
      stage_t64(A0 + (long)kt * 2, as_bytes, As, tid);
    stage_t64(B0 + (long)kt * 2, bs, Bs, tid);
    __syncthreads();
    short8 af[2], bf[2];
#pragma unroll
    for (int i = 0; i < 2; ++i) {
      af[i] = *(const short8*)(As + (mw + i * 16 + lane15) * 64 + quad * 16);
      bf[i] = *(const short8*)(Bs + (nw + i * 16 + lane15) * 64 + quad * 16);
    }
#pragma unroll
    for (int mi = 0; mi < 2; ++mi)
#pragma unroll
      for (int ni = 0; ni < 2; ++ni)
        acc[mi][ni] = __builtin_amdgcn_mfma_f32_16x16x32_bf16(
            af[mi], bf[ni], acc[mi][ni], 0, 0, 0);
    __syncthreads();
  }
}

// ---- setup: z = 0, cnt = 0, weight transposes (single dispatch) ------------
// hwT [KER][EMB], w1T [3][MID][DF], w2T [3][KER][MID], gT [EMB][3*KER]
__global__ __launch_bounds__(256) void k_setup(
    const float* h_w, const float* w1s, const float* w1a, const float* w1n,
    const float* w2s, const float* w2a, const float* w2n, const float* gs,
    const float* ga, const float* gn, u16* hwT, u16* w1T, u16* w2T, u16* gT,
    float4* z, int* cnt) {
  const int b = blockIdx.x;
  if (b < 6144) {
    z[b * 256 + threadIdx.x] = (float4){0.f, 0.f, 0.f, 0.f};
    return;
  }
  if (b < 6240) {
    cnt[(b - 6144) * 256 + threadIdx.x] = 0;
    return;
  }
  int i = (b - 6240) * 256 + threadIdx.x;
  if (i < 65536) {
    int n = i >> 8, k = i & 255;
    hwT[i] = f2bf(h_w[k * 256 + n]);
    return;
  }
  int j = i - 65536;
  if (j < 24576) {
    int t = j >> 13, jj = j & 8191, n = jj >> 6, k = jj & 63;
    const float* w1 = t == 0 ? w1s : (t == 1 ? w1a : w1n);
    w1T[j] = f2bf(w1[k * 128 + n]);
    return;
  }
  j -= 24576;
  if (j < 98304) {
    int t = j >> 15, jj = j & 32767, n = jj >> 7, k = jj & 127;
    const float* w2 = t == 0 ? w2s : (t == 1 ? w2a : w2n);
    w2T[j] = f2bf(w2[k * 256 + n]);
    return;
  }
  j -= 98304;
  if (j < 196608) {
    int n = j / 768, q = j % 768, t = q >> 8, k = q & 255;
    const float* g = t == 0 ? gs : (t == 1 ? ga : gn);
    gT[j] = f2bf(g[k * 256 + n]);
  }
}

// ----------------------------- sort kernels ---------------------------------
__global__ __launch_bounds__(256) void k_hist(const int* r0, const int* r1,
                                              const int* r2, int* cnt) {
  const int t = blockIdx.z;
  const int* rcv = t == 0 ? r0 : (t == 1 ? r1 : r2);
  const int e = blockIdx.x * 256 + threadIdx.x;
  atomicAdd(&cnt[t * N_ELEC + rcv[e]], 1);
}

__global__ __launch_bounds__(256) void k_scan(const int* cnt, int* rowptr,
                                              int* cursor) {
  const int t = blockIdx.x, tid = threadIdx.x;
  __shared__ int part[256];
  const int* c = cnt + t * N_ELEC;
  int s = 0;
#pragma unroll
  for (int i = 0; i < 32; ++i) s += c[tid * 32 + i];
  part[tid] = s;
  __syncthreads();
  for (int off = 1; off < 256; off <<= 1) {
    int v = (tid >= off) ? part[tid - off] : 0;
    __syncthreads();
    part[tid] += v;
    __syncthreads();
  }
  int run = (tid == 0) ? 0 : part[tid - 1];
  int* rp = rowptr + t * RPS;
  int* cu = cursor + t * N_ELEC;
  for (int i = 0; i < 32; ++i) {
    rp[tid * 32 + i] = run;
    cu[tid * 32 + i] = run;
    run += c[tid * 32 + i];
  }
  if (tid == 255) rp[N_ELEC] = run;  // = NEDGE
}

// packed sorted-edge record: bits [16:0]=e, [29:17]=snd, [42:30]=rcv
__global__ __launch_bounds__(256) void k_place(const int* r0, const int* r1,
                                               const int* r2, const int* s0,
                                               const int* s1, const int* s2,
                                               int* cursor, u64* pk) {
  const int t = blockIdx.z;
  const int* rcv = t == 0 ? r0 : (t == 1 ? r1 : r2);
  const int* snd = t == 0 ? s0 : (t == 1 ? s1 : s2);
  const int e = blockIdx.x * 256 + threadIdx.x;
  const int rr = rcv[e];
  const int pos = atomicAdd(&cursor[t * N_ELEC + rr], 1);
  pk[t * NEDGE + pos] =
      (u64)(unsigned)e | ((u64)(unsigned)snd[e] << 17) | ((u64)(unsigned)rr << 30);
}

// ------------------- he = electrons @ h_w  (64x64 tiles) --------------------
__global__ __launch_bounds__(256) void k_he(const float* elec, const u16* hwT,
                                            u16* he) {
  __shared__ char As[4096], Bs[4096];
  f32x4 acc[2][2];
#pragma unroll
  for (int i = 0; i < 2; ++i)
#pragma unroll
    for (int j = 0; j < 2; ++j) acc[i][j] = (f32x4){0.f, 0.f, 0.f, 0.f};
  const int m0 = blockIdx.x * 64, n0 = blockIdx.y * 64;
  gemm64<true>(nullptr, 0, elec + (long)m0 * 256, 256,
               (const char*)hwT + (long)n0 * 512, 512, 256, As, Bs, acc,
               threadIdx.x);
  const int l = threadIdx.x & 63, lane15 = l & 15, quad = l >> 4,
            wv = threadIdx.x >> 6;
  const int mw = (wv >> 1) * 32, nw = (wv & 1) * 32;
#pragma unroll
  for (int mi = 0; mi < 2; ++mi)
#pragma unroll
    for (int r = 0; r < 4; ++r) {
      const int row = m0 + mw + mi * 16 + quad * 4 + r;
#pragma unroll
      for (int ni = 0; ni < 2; ++ni) {
        const int col = n0 + nw + ni * 16 + lane15;
        he[row * 256 + col] = f2bf(acc[mi][ni][r]);
      }
    }
}

// ---- fused edge kernel (R15: 8 waves, full-width hc, zacc store-flush) -----
// 512 threads, 8 waves. Wave GEMM tile: 32 rows x 64 cols (acc[2][4]).
// LDS 79.4KB -> 2 blocks/CU = 16 waves/CU. 11 barriers/tile.
__global__ __launch_bounds__(512, 4) void k_edge(
    const float* d0, const float* d1, const float* d2, const float* b0,
    const float* b1p, const float* b2, const u16* w1T, const u16* w2T,
    const u16* he, const float* nucf, const u64* pk, float* z) {
  __shared__ __align__(16) char mid[128 * CSTR];   // 34816 B
  __shared__ __align__(16) char hc[128 * CSTR];    // 34816 B (all rows)
  __shared__ __align__(16) float zacc[NSLOT][128]; //  8192 B
  __shared__ int snd_l[128], rcv_l[128], slot_l[128];
  __shared__ int rcv_slot[NSLOT];
  __shared__ int cnt_w[2], nslots_s;

  const int t = blockIdx.z;
  const int m0 = blockIdx.x * 128;
  const int tid = threadIdx.x;  // 0..511
  const float* dist = t == 0 ? d0 : (t == 1 ? d1 : d2);
  const float* bias = t == 0 ? b0 : (t == 1 ? b1p : b2);
  const u16* w1t = w1T + t * 8192;   // [128][64]
  const u16* w2t = w2T + t * 32768;  // [256][128]
  const bool is_nuc = (t == 2);
  const u64* pkt = pk + (size_t)t * NEDGE + m0;

  // tile meta: one packed load per edge
  if (tid < 128) {
    const u64 rec = pkt[tid];
    snd_l[tid] = (int)((rec >> 17) & 0x1FFFu);
    rcv_l[tid] = (int)(rec >> 30);
  }
  // zero zacc (2048 f32, 4/thread)
  {
    float* zf = &zacc[0][0];
#pragma unroll
    for (int i = 0; i < 4; ++i) zf[i * 512 + tid] = 0.f;
  }
  // stage gathered dist rows as two K-halves [128][32] bf16 into mid[0:16K]
  int rows[2];
#pragma unroll
  for (int s = 0; s < 2; ++s)
    rows[s] = (int)(pkt[(s * 512 + tid) >> 3] & 0x1FFFFu);
#pragma unroll
  for (int j = 0; j < 2; ++j)
#pragma unroll
    for (int s = 0; s < 2; ++s) {
      const int idx = s * 512 + tid, row = idx >> 3, ch = idx & 7;
      const float4 v =
          *(const float4*)(dist + (long)rows[s] * 64 + j * 32 + ch * 4);
      uint2 p;
      p.x = pkbf(v.x, v.y);
      p.y = pkbf(v.z, v.w);
      *(uint2*)(mid + j * 8192 + row * 64 + ch * 8) = p;
    }
  bar_lds();  // bar1: dist halves + meta visible

  // receiver-slot assignment (waves 0-1): slot = #changes at or before row
  {
    bool flag = false;
    int pre = 0;
    if (tid < 128) {
      const int rcv = rcv_l[tid];
      flag = (tid > 0) && (rcv != rcv_l[tid - 1]);
      const u64 m = __ballot(flag);
      pre = (int)__popcll(m & ((1ull << (tid & 63)) - 1ull));
      if ((tid & 63) == 0) cnt_w[tid >> 6] = (int)__popcll(m);
    }
    bar_lds();  // bar2: cnt_w visible
    if (tid < 128) {
      const int slot = pre + (flag ? 1 : 0) + ((tid >= 64) ? cnt_w[0] : 0);
      slot_l[tid] = slot;
      if ((flag || tid == 0) && slot < NSLOT) rcv_slot[slot] = rcv_l[tid];
      if (tid == 0) nslots_s = cnt_w[0] + cnt_w[1] + 1;
    }
  }
  // slot_l/rcv_slot/nslots_s consumed only after bar3/bar4 below

  const int l = tid & 63, lane15 = l & 15, quad = l >> 4, wv = tid >> 6;
  const int mw = (wv >> 1) * 32;  // 4-way M split (32 rows/wave)
  const int nw = (wv & 1) * 64;   // 2-way N split (64 cols/wave)

  // GEMM1: [128,64] @ [64,128] -> acc[2][4]  (B = w1t global, L2-hot)
  f32x4 acc[2][4];
#pragma unroll
  for (int i = 0; i < 2; ++i)
#pragma unroll
    for (int j = 0; j < 4; ++j) acc[i][j] = (f32x4){0.f, 0.f, 0.f, 0.f};
#pragma unroll
  for (int j = 0; j < 2; ++j) {
    short8 af[2], bf[4];
#pragma unroll
    for (int i = 0; i < 2; ++i)
      af[i] = *(const short8*)(mid + j * 8192 + (mw + i * 16 + lane15) * 64 +
                               quad * 16);
#pragma unroll
    for (int i = 0; i < 4; ++i)
      bf[i] = *(const short8*)(w1t + (nw + i * 16 + lane15) * 64 + j * 32 +
                               quad * 8);
#pragma unroll
    for (int mi = 0; mi < 2; ++mi)
#pragma unroll
      for (int ni = 0; ni < 4; ++ni)
        acc[mi][ni] = __builtin_amdgcn_mfma_f32_16x16x32_bf16(
            af[mi], bf[ni], acc[mi][ni], 0, 0, 0);
  }
  bar_lds();  // bar3: all waves done reading dist halves

  // bias + SSP -> mid (272 B rows)
#pragma unroll
  for (int mi = 0; mi < 2; ++mi)
#pragma unroll
    for (int r = 0; r < 4; ++r) {
      const int row = mw + mi * 16 + quad * 4 + r;
#pragma unroll
      for (int ni = 0; ni < 4; ++ni) {
        const int col = nw + ni * 16 + lane15;
        const float x = acc[mi][ni][r] + bias[col];
        *(u16*)(mid + row * CSTR + col * 2) = f2bf(ssp_fast(x));
      }
    }
  bar_lds();  // bar4: mid visible to all waves

  for (int n0 = 0; n0 < 256; n0 += 128) {
    // GEMM2: A = mid (LDS), B = w2t cols n0.. (global, L2-hot)
#pragma unroll
    for (int i = 0; i < 2; ++i)
#pragma unroll
      for (int j = 0; j < 4; ++j) acc[i][j] = (f32x4){0.f, 0.f, 0.f, 0.f};
#pragma unroll
    for (int kt = 0; kt < 128; kt += 32) {
      short8 af[2], bf[4];
#pragma unroll
      for (int i = 0; i < 2; ++i)
        af[i] = *(const short8*)(mid + (mw + i * 16 + lane15) * CSTR + kt * 2 +
                                 quad * 16);
#pragma unroll
      for (int i = 0; i < 4; ++i)
        bf[i] = *(const short8*)(w2t + (n0 + nw + i * 16 + lane15) * 128 + kt +
                                 quad * 8);
#pragma unroll
      for (int mi = 0; mi < 2; ++mi)
#pragma unroll
        for (int ni = 0; ni < 4; ++ni)
          acc[mi][ni] = __builtin_amdgcn_mfma_f32_16x16x32_bf16(
              af[mi], bf[ni], acc[mi][ni], 0, 0, 0);
    }

    // stage all 128 src rows (cols n0..n0+128) into hc: 2048 x 16B, 4/thread
    if (!is_nuc) {
#pragma unroll
      for (int c = 0; c < 4; ++c) {
        const int chunk = c * 512 + tid;
        const int row = chunk >> 4, off = chunk & 15;
        const uint4 v =
            *(const uint4*)((const char*)he + (size_t)snd_l[row] * 512 +
                            n0 * 2 + off * 16);
        *(uint4*)(hc + row * CSTR + off * 16) = v;
      }
    } else {
#pragma unroll
      for (int c = 0; c < 4; ++c) {
        const int chunk = c * 512 + tid;
        const int row = chunk >> 4, off = chunk & 15;
        const char* src = (const char*)nucf + (size_t)snd_l[row] * 1024 +
                          n0 * 4 + off * 32;
        const float4 a = *(const float4*)src;
        const float4 b = *(const float4*)(src + 16);
        uint4 p;
        p.x = pkbf(a.x, a.y);
        p.y = pkbf(a.z, a.w);
        p.z = pkbf(b.x, b.y);
        p.w = pkbf(b.z, b.w);
        *(uint4*)(hc + row * CSTR + off * 16) = p;
      }
    }
    bar_lds();  // bar5: hc visible

    // in-place multiply: every wave owns its own fragment rows (32) x cols
#pragma unroll
    for (int mi = 0; mi < 2; ++mi)
#pragma unroll
      for (int r = 0; r < 4; ++r) {
        const int row = mw + mi * 16 + quad * 4 + r;  // 0..127
#pragma unroll
        for (int ni = 0; ni < 4; ++ni) {
          const int col = nw + ni * 16 + lane15;
          u16* p = (u16*)(hc + row * CSTR) + col;
          *p = f2bf(acc[mi][ni][r] * bf2f(*p));
        }
      }
    bar_lds();  // bar6: weh visible

    // segmented reduce: 8 waves x 16-row strips; lane owns col pair.
    // Segment flushes go to zacc via ds_add (fire-and-forget until bar);
    // overflow slots (>=NSLOT, rare) go straight to global atomics.
    {
      const int cp = l;
      const int rbeg = wv * 16;
      float a0 = 0.f, a1 = 0.f;
      int cs = slot_l[rbeg];
#pragma unroll
      for (int i = 0; i < 16; ++i) {
        const int row = rbeg + i;
        const unsigned p = *(const unsigned*)(hc + row * CSTR + cp * 4);
        a0 += __uint_as_float(p << 16);
        a1 += __uint_as_float(p & 0xffff0000u);
        const int ns = (i + 1 < 16) ? slot_l[row + 1] : -1;
        if (ns != cs) {
          if (cs < NSLOT) {
            atomicAdd(&zacc[cs][cp * 2], a0);
            atomicAdd(&zacc[cs][cp * 2 + 1], a1);
          } else {
            float* zp = z + (size_t)rcv_l[row] * 768 + t * 256 + n0 + cp * 2;
            unsafeAtomicAdd(zp, a0);
            unsafeAtomicAdd(zp + 1, a1);
          }
          a0 = a1 = 0.f;
          cs = ns;
        }
      }
    }
    bar_lds();  // bar7: zacc adds complete

    // flush zacc -> z. Interior slots (receiver fully inside this tile by
    // sort order) = plain float4 stores; slot 0 / last slot = atomics.
    {
      const int nsl = nslots_s;
      const int s = tid >> 5, c0 = (tid & 31) * 4;
      if (s < nsl && s < NSLOT) {
        const int r = rcv_slot[s];
        float* zp = z + (size_t)r * 768 + t * 256 + n0 + c0;
        if (s == 0 || s == nsl - 1) {
#pragma unroll
          for (int jj = 0; jj < 4; ++jj)
            unsafeAtomicAdd(zp + jj, zacc[s][c0 + jj]);
        } else {
          *(float4*)zp = *(float4*)&zacc[s][c0];
        }
      }
    }
    if (n0 == 0) {
      bar_lds();  // bar8: flush reads done before re-zero
      float* zf = &zacc[0][0];
#pragma unroll
      for (int i = 0; i < 4; ++i) zf[i * 512 + tid] = 0.f;
      // rezero completes before next reduce (bar5'/bar6' intervene)
    }
  }
}

// ------ out = electrons_f32 + bf16(z) @ gT^T  (f32, 64x64 tiles) ------------
__global__ __launch_bounds__(256) void k_final(const float* z, const u16* gT,
                                               const float* elec, float* out) {
  __shared__ char As[4096], Bs[4096];
  f32x4 acc[2][2];
#pragma unroll
  for (int i = 0; i < 2; ++i)
#pragma unroll
    for (int j = 0; j < 2; ++j) acc[i][j] = (f32x4){0.f, 0.f, 0.f, 0.f};
  const int m0 = blockIdx.x * 64, n0 = blockIdx.y * 64;
  gemm64<true>(nullptr, 0, z + (long)m0 * 768, 768,
               (const char*)gT + (long)n0 * 1536, 1536, 768, As, Bs, acc,
               threadIdx.x);
  const int l = threadIdx.x & 63, lane15 = l & 15, quad = l >> 4,
            wv = threadIdx.x >> 6;
  const int mw = (wv >> 1) * 32, nw = (wv & 1) * 32;
#pragma unroll
  for (int mi = 0; mi < 2; ++mi)
#pragma unroll
    for (int r = 0; r < 4; ++r) {
      const int row = m0 + mw + mi * 16 + quad * 4 + r;
#pragma unroll
      for (int ni = 0; ni < 2; ++ni) {
        const int col = n0 + nw + ni * 16 + lane15;
        out[row * 256 + col] = acc[mi][ni][r] + elec[row * 256 + col];
      }
    }
}

// ---------------------------------------------------------------------------
extern "C" void kernel_launch(void* const* d_in, const int* in_sizes, int n_in,
                              void* d_out, int out_size, void* d_ws,
                              size_t ws_size, hipStream_t stream) {
  int I_dist[3], I_w1[3], I_b1[3], I_w2[3], I_g[3], I_hw;
  if (in_sizes[3] == 64 * 128) {  // setup_inputs() dict order
    for (int t = 0; t < 3; ++t) {
      I_dist[t] = 2 + t * 5 + 0;
      I_w1[t] = 2 + t * 5 + 1;
      I_b1[t] = 2 + t * 5 + 2;
      I_w2[t] = 2 + t * 5 + 3;
      I_g[t] = 2 + t * 5 + 4;
    }
    I_hw = 17;
  } else {  // reference signature order
    I_dist[0] = 2; I_dist[1] = 3; I_dist[2] = 4;
    I_w1[0] = 5;  I_b1[0] = 6;  I_w2[0] = 7;
    I_w1[1] = 8;  I_b1[1] = 9;  I_w2[1] = 10;
    I_w1[2] = 11; I_b1[2] = 12; I_w2[2] = 13;
    I_g[0] = 14; I_g[1] = 15; I_g[2] = 16;
    I_hw = 17;
  }
  const int I_snd[3] = {18, 19, 20};
  const int I_rcv[3] = {21, 22, 23};

  char* ws = (char*)d_ws;
  // workspace layout (bytes). Total ~34 MB.
  u16* he = (u16*)(ws + 0);              //   4,194,304
  u16* hwT = (u16*)(ws + 4194304);       //     131,072
  u16* w1T = (u16*)(ws + 4325376);       //      49,152
  u16* w2T = (u16*)(ws + 4374528);       //     196,608
  u16* gT = (u16*)(ws + 4571136);        //     393,216
  float* z = (float*)(ws + 4964352);     //  25,165,824
  int* cnt = (int*)(ws + 30130176);      //      98,304
  int* rowptr = (int*)(ws + 30228480);   //      99,072
  int* cursor = (int*)(ws + 30327552);   //      98,304
  u64* pk = (u64*)(ws + 30425856);       //   3,145,728

  const float* elec = (const float*)d_in[0];
  const float* nuc = (const float*)d_in[1];
  const int* s0 = (const int*)d_in[I_snd[0]];
  const int* s1 = (const int*)d_in[I_snd[1]];
  const int* s2 = (const int*)d_in[I_snd[2]];
  const int* r0 = (const int*)d_in[I_rcv[0]];
  const int* r1 = (const int*)d_in[I_rcv[1]];
  const int* r2 = (const int*)d_in[I_rcv[2]];

  // z=0 (6144) + cnt=0 (96) + weight transposes (1504) in one dispatch
  k_setup<<<7744, 256, 0, stream>>>(
      (const float*)d_in[I_hw], (const float*)d_in[I_w1[0]],
      (const float*)d_in[I_w1[1]], (const float*)d_in[I_w1[2]],
      (const float*)d_in[I_w2[0]], (const float*)d_in[I_w2[1]],
      (const float*)d_in[I_w2[2]], (const float*)d_in[I_g[0]],
      (const float*)d_in[I_g[1]], (const float*)d_in[I_g[2]], hwT, w1T, w2T,
      gT, (float4*)z, cnt);

  // counting sort by receiver, per type
  k_hist<<<dim3(NEDGE / 256, 1, 3), 256, 0, stream>>>(r0, r1, r2, cnt);
  k_scan<<<3, 256, 0, stream>>>(cnt, rowptr, cursor);
  k_place<<<dim3(NEDGE / 256, 1, 3), 256, 0, stream>>>(r0, r1, r2, s0, s1, s2,
                                                       cursor, pk);

  k_he<<<dim3(N_ELEC / 64, 4), 256, 0, stream>>>(elec, hwT, he);

  k_edge<<<dim3(NEDGE / 128, 1, 3), 512, 0, stream>>>(
      (const float*)d_in[I_dist[0]], (const float*)d_in[I_dist[1]],
      (const float*)d_in[I_dist[2]], (const float*)d_in[I_b1[0]],
      (const float*)d_in[I_b1[1]], (const float*)d_in[I_b1[2]], w1T, w2T, he,
      nuc, pk, z);

  k_final<<<dim3(N_ELEC / 64, 4), 256, 0, stream>>>(z, gT, elec,
                                                    (float*)d_out);
}

// Round 8
// 458.117 us; speedup vs baseline: 1.0160x; 1.0160x over previous
//
#include <hip/hip_runtime.h>
#include <stdint.h>

// ---------------------------------------------------------------------------
// SchNetLayer on MI355X (gfx950).
// I/O: float tensors f32, indices int32. Internal: bf16 MFMA.
//
// R2: atomic scatter = atomic-rate bound -> counting sort.
// R3: libm softplus -> native v_exp/v_log.
// R4/R5: fuse gather/MLP/multiply/reduce into k_edge.
// R6-R8: LDS/occupancy tuning -> 128-edge tile, 3 blocks/CU, 159us.
// R9: lgkmcnt-only barriers: NEUTRAL (drains hidden by resident blocks).
// R10: 512thr+8-row strips: REGRESSED (more flushes, more phases).
// R11-R13: zacc v1: REGRESSED (29 barriers; + rule-#20 spill in R11/12).
// R14: TILE=64 @52% occupancy: NEUTRAL-worse. Occupancy isn't the lever.
// R15: zacc v2, atomics truly gone (WRITE 95->46MB) yet 252us: SLOWER.
//      Atomic-rate theory FALSIFIED. Pattern across R10-R15: time tracks
//      PHASE COUNT + LDS/VALU issue work, not atomics/occupancy/drains.
//      R8's cost center: hc staging (64KB LDS/tile) + 32K-elem scalar u16
//      RMW multiply with bf16 bit-twiddles — pure re-layout overhead.
// R16: delete the weh round-trip. GEMM2 acc -> wec (LDS, one fragment
//      write, like SSP). Reduce reads wec col-pairs + he/nuc DIRECTLY
//      from global (same bytes hc fetched) and multiplies in-register.
//      Removes hc staging, the whole RMW phase, 8 of 15 barriers.
//      512thr/8waves, 128-edge tile; mid+wec=70.7KB -> 2 blocks/CU
//      (16 waves/CU). Direct fire-and-forget atomics (R8 flush shape).
//
// Pipeline:
//   k_setup: z=0, cnt=0, weight transposes (one dispatch)
//   sort:  k_hist, k_scan, k_place        (counting sort by receiver)
//   k_he   : he = bf16(electrons) @ h_w   [8192,256] bf16   (64x64 tiles)
//   k_edge : per 128-edge tile: mid=SSP(dist[perm]@w1+b1); per n0:
//            we=mid@w2 -> wec; reduce: we*he(global) 16-row strips ->
//            fire-and-forget z atomics
//   k_final: out = electrons + bf16(z) @ g_catT  f32 out   (64x64 tiles)
// ---------------------------------------------------------------------------

#define N_ELEC 8192
#define N_NUC  512
#define EMB    256
#define KER    256
#define DF     64
#define MID    128
#define NEDGE  131072
#define RPS    8256   // rowptr per-type stride (ints)
#define CSTR   272    // LDS row stride bytes for 128-col u16 tiles (+16 pad)

using u16 = unsigned short;
using u64 = unsigned long long;
typedef short short8 __attribute__((ext_vector_type(8)));
typedef float f32x4 __attribute__((ext_vector_type(4)));

__device__ __forceinline__ float bf2f(u16 h) {
  return __uint_as_float(((unsigned)h) << 16);
}
__device__ __forceinline__ u16 f2bf(float f) {
  unsigned u = __float_as_uint(f);
  return (u16)((u + 0x7FFFu + ((u >> 16) & 1u)) >> 16);  // RNE
}
__device__ __forceinline__ unsigned pkbf(float a, float b) {
  return ((unsigned)f2bf(b) << 16) | (unsigned)f2bf(a);
}
// fast shifted softplus: log(0.5 e^x + 0.5), stable, native v_exp/v_log.
__device__ __forceinline__ float ssp_fast(float x) {
  const float e = __expf(-fabsf(x));
  return fmaxf(x, 0.f) + __logf(fmaf(0.5f, e, 0.5f));
}

// LDS-only workgroup barrier (R9): no vmcnt drain; all cross-wave deps in
// k_edge go through LDS; per-thread global loads are ordered by the
// compiler's own vmcnt waits; z atomics are fire-and-forget.
// sched_barrier(0) both sides per rule #18.
__device__ __forceinline__ void bar_lds() {
  __builtin_amdgcn_sched_barrier(0);
  asm volatile("s_waitcnt lgkmcnt(0)" ::: "memory");
  __builtin_amdgcn_s_barrier();
  __builtin_amdgcn_sched_barrier(0);
}

// ---- 64x64 tile GEMM machinery (k_he / k_final) ----------------------------
__device__ __forceinline__ void stage_t64(const char* g0, long stride,
                                          char* lds, int tid) {
  const int l = tid & 63, w = tid >> 6;
  const int r = w * 16 + (l >> 2);
  const int cb = (l & 3) * 16;
  __builtin_amdgcn_global_load_lds(
      (const __attribute__((address_space(1))) unsigned*)(g0 +
                                                          (long)r * stride +
                                                          cb),
      (__attribute__((address_space(3))) unsigned*)(lds + w * 1024), 16, 0, 0);
}
__device__ __forceinline__ void stage_f64(const float* g0, int stride_e,
                                          int kt, char* lds, int tid) {
#pragma unroll
  for (int k = 0; k < 4; ++k) {
    const int idx2 = k * 256 + tid;
    const int row = idx2 >> 4, cp = idx2 & 15;
    const float2 v = *(const float2*)(g0 + (long)row * stride_e + kt + cp * 2);
    *(unsigned*)(lds + row * 64 + cp * 4) = pkbf(v.x, v.y);
  }
}
template <bool A_F32>
__device__ __forceinline__ void gemm64(const char* A0, long as_bytes,
                                       const float* Af, int as_elems,
                                       const char* B0, long bs, int K,
                                       char* As, char* Bs, f32x4 acc[2][2],
                                       int tid) {
  const int l = tid & 63, lane15 = l & 15, quad = l >> 4, wv = tid >> 6;
  const int mw = (wv >> 1) * 32, nw = (wv & 1) * 32;
  for (int kt = 0; kt < K; kt += 32) {
    if (A_F32)
      stage_f64(Af, as_elems, kt, As, tid);
    else
      stage_t64(A0 + (long)kt * 2, as_bytes, As, tid);
    stage_t64(B0 + (long)kt * 2, bs, Bs, tid);
    __syncthreads();
    short8 af[2], bf[2];
#pragma unroll
    for (int i = 0; i < 2; ++i) {
      af[i] = *(const short8*)(As + (mw + i * 16 + lane15) * 64 + quad * 16);
      bf[i] = *(const short8*)(Bs + (nw + i * 16 + lane15) * 64 + quad * 16);
    }
#pragma unroll
    for (int mi = 0; mi < 2; ++mi)
#pragma unroll
      for (int ni = 0; ni < 2; ++ni)
        acc[mi][ni] = __builtin_amdgcn_mfma_f32_16x16x32_bf16(
            af[mi], bf[ni], acc[mi][ni], 0, 0, 0);
    __syncthreads();
  }
}

// ---- setup: z = 0, cnt = 0, weight transposes (single dispatch) ------------
// hwT [KER][EMB], w1T [3][MID][DF], w2T [3][KER][MID], gT [EMB][3*KER]
__global__ __launch_bounds__(256) void k_setup(
    const float* h_w, const float* w1s, const float* w1a, const float* w1n,
    const float* w2s, const float* w2a, const float* w2n, const float* gs,
    const float* ga, const float* gn, u16* hwT, u16* w1T, u16* w2T, u16* gT,
    float4* z, int* cnt) {
  const int b = blockIdx.x;
  if (b < 6144) {
    z[b * 256 + threadIdx.x] = (float4){0.f, 0.f, 0.f, 0.f};
    return;
  }
  if (b < 6240) {
    cnt[(b - 6144) * 256 + threadIdx.x] = 0;
    return;
  }
  int i = (b - 6240) * 256 + threadIdx.x;
  if (i < 65536) {
    int n = i >> 8, k = i & 255;
    hwT[i] = f2bf(h_w[k * 256 + n]);
    return;
  }
  int j = i - 65536;
  if (j < 24576) {
    int t = j >> 13, jj = j & 8191, n = jj >> 6, k = jj & 63;
    const float* w1 = t == 0 ? w1s : (t == 1 ? w1a : w1n);
    w1T[j] = f2bf(w1[k * 128 + n]);
    return;
  }
  j -= 24576;
  if (j < 98304) {
    int t = j >> 15, jj = j & 32767, n = jj >> 7, k = jj & 127;
    const float* w2 = t == 0 ? w2s : (t == 1 ? w2a : w2n);
    w2T[j] = f2bf(w2[k * 256 + n]);
    return;
  }
  j -= 98304;
  if (j < 196608) {
    int n = j / 768, q = j % 768, t = q >> 8, k = q & 255;
    const float* g = t == 0 ? gs : (t == 1 ? ga : gn);
    gT[j] = f2bf(g[k * 256 + n]);
  }
}

// ----------------------------- sort kernels ---------------------------------
__global__ __launch_bounds__(256) void k_hist(const int* r0, const int* r1,
                                              const int* r2, int* cnt) {
  const int t = blockIdx.z;
  const int* rcv = t == 0 ? r0 : (t == 1 ? r1 : r2);
  const int e = blockIdx.x * 256 + threadIdx.x;
  atomicAdd(&cnt[t * N_ELEC + rcv[e]], 1);
}

__global__ __launch_bounds__(256) void k_scan(const int* cnt, int* rowptr,
                                              int* cursor) {
  const int t = blockIdx.x, tid = threadIdx.x;
  __shared__ int part[256];
  const int* c = cnt + t * N_ELEC;
  int s = 0;
#pragma unroll
  for (int i = 0; i < 32; ++i) s += c[tid * 32 + i];
  part[tid] = s;
  __syncthreads();
  for (int off = 1; off < 256; off <<= 1) {
    int v = (tid >= off) ? part[tid - off] : 0;
    __syncthreads();
    part[tid] += v;
    __syncthreads();
  }
  int run = (tid == 0) ? 0 : part[tid - 1];
  int* rp = rowptr + t * RPS;
  int* cu = cursor + t * N_ELEC;
  for (int i = 0; i < 32; ++i) {
    rp[tid * 32 + i] = run;
    cu[tid * 32 + i] = run;
    run += c[tid * 32 + i];
  }
  if (tid == 255) rp[N_ELEC] = run;  // = NEDGE
}

// packed sorted-edge record: bits [16:0]=e, [29:17]=snd, [42:30]=rcv
__global__ __launch_bounds__(256) void k_place(const int* r0, const int* r1,
                                               const int* r2, const int* s0,
                                               const int* s1, const int* s2,
                                               int* cursor, u64* pk) {
  const int t = blockIdx.z;
  const int* rcv = t == 0 ? r0 : (t == 1 ? r1 : r2);
  const int* snd = t == 0 ? s0 : (t == 1 ? s1 : s2);
  const int e = blockIdx.x * 256 + threadIdx.x;
  const int rr = rcv[e];
  const int pos = atomicAdd(&cursor[t * N_ELEC + rr], 1);
  pk[t * NEDGE + pos] =
      (u64)(unsigned)e | ((u64)(unsigned)snd[e] << 17) | ((u64)(unsigned)rr << 30);
}

// ------------------- he = electrons @ h_w  (64x64 tiles) --------------------
__global__ __launch_bounds__(256) void k_he(const float* elec, const u16* hwT,
                                            u16* he) {
  __shared__ char As[4096], Bs[4096];
  f32x4 acc[2][2];
#pragma unroll
  for (int i = 0; i < 2; ++i)
#pragma unroll
    for (int j = 0; j < 2; ++j) acc[i][j] = (f32x4){0.f, 0.f, 0.f, 0.f};
  const int m0 = blockIdx.x * 64, n0 = blockIdx.y * 64;
  gemm64<true>(nullptr, 0, elec + (long)m0 * 256, 256,
               (const char*)hwT + (long)n0 * 512, 512, 256, As, Bs, acc,
               threadIdx.x);
  const int l = threadIdx.x & 63, lane15 = l & 15, quad = l >> 4,
            wv = threadIdx.x >> 6;
  const int mw = (wv >> 1) * 32, nw = (wv & 1) * 32;
#pragma unroll
  for (int mi = 0; mi < 2; ++mi)
#pragma unroll
    for (int r = 0; r < 4; ++r) {
      const int row = m0 + mw + mi * 16 + quad * 4 + r;
#pragma unroll
      for (int ni = 0; ni < 2; ++ni) {
        const int col = n0 + nw + ni * 16 + lane15;
        he[row * 256 + col] = f2bf(acc[mi][ni][r]);
      }
    }
}

// ---- fused edge kernel (R16: no weh round-trip; reduce multiplies) ---------
// 512 threads, 8 waves. Wave GEMM tile: 32 rows x 64 cols (acc[2][4]).
// LDS: mid 34816 + wec 34816 + meta 1024 = 70.7KB -> 2 blocks/CU.
// 7 barriers/tile (vs R8's 15).
__global__ __launch_bounds__(512, 4) void k_edge(
    const float* d0, const float* d1, const float* d2, const float* b0,
    const float* b1p, const float* b2, const u16* w1T, const u16* w2T,
    const u16* he, const float* nucf, const u64* pk, float* z) {
  __shared__ __align__(16) char mid[128 * CSTR];  // 34816 B: dist -> SSP mid
  __shared__ __align__(16) char wec[128 * CSTR];  // 34816 B: we (per n0)
  __shared__ int snd_l[128], rcv_l[128];

  const int t = blockIdx.z;
  const int m0 = blockIdx.x * 128;
  const int tid = threadIdx.x;  // 0..511
  const float* dist = t == 0 ? d0 : (t == 1 ? d1 : d2);
  const float* bias = t == 0 ? b0 : (t == 1 ? b1p : b2);
  const u16* w1t = w1T + t * 8192;   // [128][64]
  const u16* w2t = w2T + t * 32768;  // [256][128]
  const bool is_nuc = (t == 2);
  const u64* pkt = pk + (size_t)t * NEDGE + m0;

  // tile meta: one packed load per edge
  if (tid < 128) {
    const u64 rec = pkt[tid];
    snd_l[tid] = (int)((rec >> 17) & 0x1FFFu);
    rcv_l[tid] = (int)(rec >> 30);
  }

  // stage gathered dist rows as two K-halves [128][32] bf16 into mid[0:16K]
  int rows[2];
#pragma unroll
  for (int s = 0; s < 2; ++s)
    rows[s] = (int)(pkt[(s * 512 + tid) >> 3] & 0x1FFFFu);
#pragma unroll
  for (int j = 0; j < 2; ++j)
#pragma unroll
    for (int s = 0; s < 2; ++s) {
      const int idx = s * 512 + tid, row = idx >> 3, ch = idx & 7;
      const float4 v =
          *(const float4*)(dist + (long)rows[s] * 64 + j * 32 + ch * 4);
      uint2 p;
      p.x = pkbf(v.x, v.y);
      p.y = pkbf(v.z, v.w);
      *(uint2*)(mid + j * 8192 + row * 64 + ch * 8) = p;
    }
  bar_lds();  // bar1: dist halves + meta visible

  const int l = tid & 63, lane15 = l & 15, quad = l >> 4, wv = tid >> 6;
  const int mw = (wv >> 1) * 32;  // 4-way M split (32 rows/wave)
  const int nw = (wv & 1) * 64;   // 2-way N split (64 cols/wave)

  // GEMM1: [128,64] @ [64,128] -> acc[2][4]  (B = w1t global, L2-hot)
  f32x4 acc[2][4];
#pragma unroll
  for (int i = 0; i < 2; ++i)
#pragma unroll
    for (int j = 0; j < 4; ++j) acc[i][j] = (f32x4){0.f, 0.f, 0.f, 0.f};
#pragma unroll
  for (int j = 0; j < 2; ++j) {
    short8 af[2], bf[4];
#pragma unroll
    for (int i = 0; i < 2; ++i)
      af[i] = *(const short8*)(mid + j * 8192 + (mw + i * 16 + lane15) * 64 +
                               quad * 16);
#pragma unroll
    for (int i = 0; i < 4; ++i)
      bf[i] = *(const short8*)(w1t + (nw + i * 16 + lane15) * 64 + j * 32 +
                               quad * 8);
#pragma unroll
    for (int mi = 0; mi < 2; ++mi)
#pragma unroll
      for (int ni = 0; ni < 4; ++ni)
        acc[mi][ni] = __builtin_amdgcn_mfma_f32_16x16x32_bf16(
            af[mi], bf[ni], acc[mi][ni], 0, 0, 0);
  }
  bar_lds();  // bar2: G1 done reading dist halves (SSP overwrites mid)

  // bias + SSP -> mid (272 B rows)
#pragma unroll
  for (int mi = 0; mi < 2; ++mi)
#pragma unroll
    for (int r = 0; r < 4; ++r) {
      const int row = mw + mi * 16 + quad * 4 + r;
#pragma unroll
      for (int ni = 0; ni < 4; ++ni) {
        const int col = nw + ni * 16 + lane15;
        const float x = acc[mi][ni][r] + bias[col];
        *(u16*)(mid + row * CSTR + col * 2) = f2bf(ssp_fast(x));
      }
    }
  bar_lds();  // bar3: mid visible to all waves

  for (int n0 = 0; n0 < 256; n0 += 128) {
    // GEMM2: A = mid (LDS), B = w2t cols n0.. (global, L2-hot)
#pragma unroll
    for (int i = 0; i < 2; ++i)
#pragma unroll
      for (int j = 0; j < 4; ++j) acc[i][j] = (f32x4){0.f, 0.f, 0.f, 0.f};
#pragma unroll
    for (int kt = 0; kt < 128; kt += 32) {
      short8 af[2], bf[4];
#pragma unroll
      for (int i = 0; i < 2; ++i)
        af[i] = *(const short8*)(mid + (mw + i * 16 + lane15) * CSTR + kt * 2 +
                                 quad * 16);
#pragma unroll
      for (int i = 0; i < 4; ++i)
        bf[i] = *(const short8*)(w2t + (n0 + nw + i * 16 + lane15) * 128 + kt +
                                 quad * 8);
#pragma unroll
      for (int mi = 0; mi < 2; ++mi)
#pragma unroll
        for (int ni = 0; ni < 4; ++ni)
          acc[mi][ni] = __builtin_amdgcn_mfma_f32_16x16x32_bf16(
              af[mi], bf[ni], acc[mi][ni], 0, 0, 0);
    }

    // write we fragments -> wec (prior reduce finished at last bar)
#pragma unroll
    for (int mi = 0; mi < 2; ++mi)
#pragma unroll
      for (int r = 0; r < 4; ++r) {
        const int row = mw + mi * 16 + quad * 4 + r;
#pragma unroll
        for (int ni = 0; ni < 4; ++ni) {
          const int col = nw + ni * 16 + lane15;
          *(u16*)(wec + row * CSTR + col * 2) = f2bf(acc[mi][ni][r]);
        }
      }
    bar_lds();  // bar4: wec visible

    // segmented reduce with in-register multiply:
    // 8 waves x 16-row strips; lane owns col pair (2cp, 2cp+1) of this n0.
    // we from wec (LDS), he/nuc read DIRECTLY from global (coalesced 256B
    // per row across the wave). Fire-and-forget atomics (R8 flush shape).
    {
      const int cp = l;
      const int rbeg = wv * 16;
      float a0 = 0.f, a1 = 0.f;
      int cur = rcv_l[rbeg];
      if (!is_nuc) {
#pragma unroll
        for (int i = 0; i < 16; ++i) {
          const int row = rbeg + i;
          const unsigned wp = *(const unsigned*)(wec + row * CSTR + cp * 4);
          const unsigned hp =
              *(const unsigned*)((const char*)he +
                                 (size_t)snd_l[row] * 512 + n0 * 2 + cp * 4);
          a0 = fmaf(__uint_as_float(wp << 16), __uint_as_float(hp << 16), a0);
          a1 = fmaf(__uint_as_float(wp & 0xffff0000u),
                    __uint_as_float(hp & 0xffff0000u), a1);
          const int nxt = (i + 1 < 16) ? rcv_l[row + 1] : -1;
          if (nxt != cur) {
            float* zp = z + (size_t)cur * 768 + t * 256 + n0 + cp * 2;
            unsafeAtomicAdd(zp, a0);
            unsafeAtomicAdd(zp + 1, a1);
            a0 = a1 = 0.f;
            cur = nxt;
          }
        }
      } else {
#pragma unroll
        for (int i = 0; i < 16; ++i) {
          const int row = rbeg + i;
          const unsigned wp = *(const unsigned*)(wec + row * CSTR + cp * 4);
          const float2 hv =
              *(const float2*)(nucf + (size_t)snd_l[row] * 256 + n0 + cp * 2);
          a0 = fmaf(__uint_as_float(wp << 16), hv.x, a0);
          a1 = fmaf(__uint_as_float(wp & 0xffff0000u), hv.y, a1);
          const int nxt = (i + 1 < 16) ? rcv_l[row + 1] : -1;
          if (nxt != cur) {
            float* zp = z + (size_t)cur * 768 + t * 256 + n0 + cp * 2;
            unsafeAtomicAdd(zp, a0);
            unsafeAtomicAdd(zp + 1, a1);
            a0 = a1 = 0.f;
            cur = nxt;
          }
        }
      }
    }
    bar_lds();  // bar5: wec reads done before next n0 overwrites
  }
}

// ------ out = electrons_f32 + bf16(z) @ gT^T  (f32, 64x64 tiles) ------------
__global__ __launch_bounds__(256) void k_final(const float* z, const u16* gT,
                                               const float* elec, float* out) {
  __shared__ char As[4096], Bs[4096];
  f32x4 acc[2][2];
#pragma unroll
  for (int i = 0; i < 2; ++i)
#pragma unroll
    for (int j = 0; j < 2; ++j) acc[i][j] = (f32x4){0.f, 0.f, 0.f, 0.f};
  const int m0 = blockIdx.x * 64, n0 = blockIdx.y * 64;
  gemm64<true>(nullptr, 0, z + (long)m0 * 768, 768,
               (const char*)gT + (long)n0 * 1536, 1536, 768, As, Bs, acc,
               threadIdx.x);
  const int l = threadIdx.x & 63, lane15 = l & 15, quad = l >> 4,
            wv = threadIdx.x >> 6;
  const int mw = (wv >> 1) * 32, nw = (wv & 1) * 32;
#pragma unroll
  for (int mi = 0; mi < 2; ++mi)
#pragma unroll
    for (int r = 0; r < 4; ++r) {
      const int row = m0 + mw + mi * 16 + quad * 4 + r;
#pragma unroll
      for (int ni = 0; ni < 2; ++ni) {
        const int col = n0 + nw + ni * 16 + lane15;
        out[row * 256 + col] = acc[mi][ni][r] + elec[row * 256 + col];
      }
    }
}

// ---------------------------------------------------------------------------
extern "C" void kernel_launch(void* const* d_in, const int* in_sizes, int n_in,
                              void* d_out, int out_size, void* d_ws,
                              size_t ws_size, hipStream_t stream) {
  int I_dist[3], I_w1[3], I_b1[3], I_w2[3], I_g[3], I_hw;
  if (in_sizes[3] == 64 * 128) {  // setup_inputs() dict order
    for (int t = 0; t < 3; ++t) {
      I_dist[t] = 2 + t * 5 + 0;
      I_w1[t] = 2 + t * 5 + 1;
      I_b1[t] = 2 + t * 5 + 2;
      I_w2[t] = 2 + t * 5 + 3;
      I_g[t] = 2 + t * 5 + 4;
    }
    I_hw = 17;
  } else {  // reference signature order
    I_dist[0] = 2; I_dist[1] = 3; I_dist[2] = 4;
    I_w1[0] = 5;  I_b1[0] = 6;  I_w2[0] = 7;
    I_w1[1] = 8;  I_b1[1] = 9;  I_w2[1] = 10;
    I_w1[2] = 11; I_b1[2] = 12; I_w2[2] = 13;
    I_g[0] = 14; I_g[1] = 15; I_g[2] = 16;
    I_hw = 17;
  }
  const int I_snd[3] = {18, 19, 20};
  const int I_rcv[3] = {21, 22, 23};

  char* ws = (char*)d_ws;
  // workspace layout (bytes). Total ~34 MB.
  u16* he = (u16*)(ws + 0);              //   4,194,304
  u16* hwT = (u16*)(ws + 4194304);       //     131,072
  u16* w1T = (u16*)(ws + 4325376);       //      49,152
  u16* w2T = (u16*)(ws + 4374528);       //     196,608
  u16* gT = (u16*)(ws + 4571136);        //     393,216
  float* z = (float*)(ws + 4964352);     //  25,165,824
  int* cnt = (int*)(ws + 30130176);      //      98,304
  int* rowptr = (int*)(ws + 30228480);   //      99,072
  int* cursor = (int*)(ws + 30327552);   //      98,304
  u64* pk = (u64*)(ws + 30425856);       //   3,145,728

  const float* elec = (const float*)d_in[0];
  const float* nuc = (const float*)d_in[1];
  const int* s0 = (const int*)d_in[I_snd[0]];
  const int* s1 = (const int*)d_in[I_snd[1]];
  const int* s2 = (const int*)d_in[I_snd[2]];
  const int* r0 = (const int*)d_in[I_rcv[0]];
  const int* r1 = (const int*)d_in[I_rcv[1]];
  const int* r2 = (const int*)d_in[I_rcv[2]];

  // z=0 (6144) + cnt=0 (96) + weight transposes (1504) in one dispatch
  k_setup<<<7744, 256, 0, stream>>>(
      (const float*)d_in[I_hw], (const float*)d_in[I_w1[0]],
      (const float*)d_in[I_w1[1]], (const float*)d_in[I_w1[2]],
      (const float*)d_in[I_w2[0]], (const float*)d_in[I_w2[1]],
      (const float*)d_in[I_w2[2]], (const float*)d_in[I_g[0]],
      (const float*)d_in[I_g[1]], (const float*)d_in[I_g[2]], hwT, w1T, w2T,
      gT, (float4*)z, cnt);

  // counting sort by receiver, per type
  k_hist<<<dim3(NEDGE / 256, 1, 3), 256, 0, stream>>>(r0, r1, r2, cnt);
  k_scan<<<3, 256, 0, stream>>>(cnt, rowptr, cursor);
  k_place<<<dim3(NEDGE / 256, 1, 3), 256, 0, stream>>>(r0, r1, r2, s0, s1, s2,
                                                       cursor, pk);

  k_he<<<dim3(N_ELEC / 64, 4), 256, 0, stream>>>(elec, hwT, he);

  k_edge<<<dim3(NEDGE / 128, 1, 3), 512, 0, stream>>>(
      (const float*)d_in[I_dist[0]], (const float*)d_in[I_dist[1]],
      (const float*)d_in[I_dist[2]], (const float*)d_in[I_b1[0]],
      (const float*)d_in[I_b1[1]], (const float*)d_in[I_b1[2]], w1T, w2T, he,
      nuc, pk, z);

  k_final<<<dim3(N_ELEC / 64, 4), 256, 0, stream>>>(z, gT, elec,
                                                    (float*)d_out);
}

// Round 9
// 400.995 us; speedup vs baseline: 1.1607x; 1.1425x over previous
//
#include <hip/hip_runtime.h>
#include <stdint.h>

// ---------------------------------------------------------------------------
// SchNetLayer on MI355X (gfx950).
// I/O: float tensors f32, indices int32. Internal: bf16 MFMA.
//
// R2: atomic scatter = atomic-rate bound -> counting sort.
// R3: libm softplus -> native v_exp/v_log.
// R4/R5: fuse gather/MLP/multiply/reduce into k_edge.
// R6-R8: LDS/occupancy tuning -> 128-edge tile, 3 blocks/CU, 159us.
// R9: lgkmcnt-only barriers: NEUTRAL.
// R10-R16: five k_edge redesigns (8 waves, zacc LDS accumulator, TILE=64,
//      no-weh-round-trip) ALL lose to R8's 159us. Levers individually
//      falsified: occupancy (R14), atomic rate (R15), barrier drains (R9),
//      LDS round-trip (R16). Every 512-thr variant < every 256-thr variant.
//      R8 is the local optimum of this family. STOP REDESIGNING K_EDGE.
// R17: pivot to the unoptimized ~244us tail. k_final re-read 4x its A
//      (z f32, 100MB HBM for a 25MB tensor: 4 n-blocks per A-tile, 128
//      apart in dispatch order -> no L2 reuse); k_he same (32MB for 8MB).
//      Retile both to 32-row x 256-col output tiles (256 blocks): A staged
//      once, B read per-fragment from global (L2-resident, like k_edge's
//      w2t). k_edge: exact R8/R9 revert + pk-u64 meta (orthogonal win).
//
// Pipeline:
//   k_setup: z=0, cnt=0, weight transposes (one dispatch)
//   sort:  k_hist, k_scan, k_place        (counting sort by receiver)
//   k_he   : he = bf16(electrons) @ h_w   [8192,256] bf16  (32x256 tiles)
//   k_edge : per 128-edge tile (sorted): mid=SSP(dist[perm]@w1+b1) in LDS;
//            for n0 in {0,128}: we=mid@w2; for half in {0,1}: stage 64
//            src rows, weh=we*src, 16-row-strip segmented reduce -> z atomics
//   k_final: out = electrons + bf16(z) @ g_catT  f32 out  (32x256 tiles)
// ---------------------------------------------------------------------------

#define N_ELEC 8192
#define N_NUC  512
#define EMB    256
#define KER    256
#define DF     64
#define MID    128
#define NEDGE  131072
#define RPS    8256   // rowptr per-type stride (ints)
#define CSTR   272    // LDS row stride bytes for 128-col u16 tiles (+16 pad)

using u16 = unsigned short;
using u64 = unsigned long long;
typedef short short8 __attribute__((ext_vector_type(8)));
typedef float f32x4 __attribute__((ext_vector_type(4)));

__device__ __forceinline__ float bf2f(u16 h) {
  return __uint_as_float(((unsigned)h) << 16);
}
__device__ __forceinline__ u16 f2bf(float f) {
  unsigned u = __float_as_uint(f);
  return (u16)((u + 0x7FFFu + ((u >> 16) & 1u)) >> 16);  // RNE
}
__device__ __forceinline__ unsigned pkbf(float a, float b) {
  return ((unsigned)f2bf(b) << 16) | (unsigned)f2bf(a);
}
// fast shifted softplus: log(0.5 e^x + 0.5), stable, native v_exp/v_log.
__device__ __forceinline__ float ssp_fast(float x) {
  const float e = __expf(-fabsf(x));
  return fmaxf(x, 0.f) + __logf(fmaf(0.5f, e, 0.5f));
}

// LDS-only workgroup barrier (R9, neutral but never harmful): no vmcnt
// drain; cross-wave deps in k_edge are LDS-only; z atomics fire-and-forget.
__device__ __forceinline__ void bar_lds() {
  __builtin_amdgcn_sched_barrier(0);
  asm volatile("s_waitcnt lgkmcnt(0)" ::: "memory");
  __builtin_amdgcn_s_barrier();
  __builtin_amdgcn_sched_barrier(0);
}

// stage 32 rows x 32 cols of an f32 matrix (cols kt..kt+31) into LDS as
// bf16 [32][32] (64B rows): 512 col-pairs, 2 per thread.
__device__ __forceinline__ void stage_f32x32(const float* g0, int stride_e,
                                             int kt, char* lds, int tid) {
#pragma unroll
  for (int k = 0; k < 2; ++k) {
    const int idx2 = k * 256 + tid;
    const int row = idx2 >> 4, cp = idx2 & 15;
    const float2 v = *(const float2*)(g0 + (long)row * stride_e + kt + cp * 2);
    *(unsigned*)(lds + row * 64 + cp * 4) = pkbf(v.x, v.y);
  }
}

// ---- setup: z = 0, cnt = 0, weight transposes (single dispatch) ------------
// hwT [KER][EMB], w1T [3][MID][DF], w2T [3][KER][MID], gT [EMB][3*KER]
__global__ __launch_bounds__(256) void k_setup(
    const float* h_w, const float* w1s, const float* w1a, const float* w1n,
    const float* w2s, const float* w2a, const float* w2n, const float* gs,
    const float* ga, const float* gn, u16* hwT, u16* w1T, u16* w2T, u16* gT,
    float4* z, int* cnt) {
  const int b = blockIdx.x;
  if (b < 6144) {
    z[b * 256 + threadIdx.x] = (float4){0.f, 0.f, 0.f, 0.f};
    return;
  }
  if (b < 6240) {
    cnt[(b - 6144) * 256 + threadIdx.x] = 0;
    return;
  }
  int i = (b - 6240) * 256 + threadIdx.x;
  if (i < 65536) {
    int n = i >> 8, k = i & 255;
    hwT[i] = f2bf(h_w[k * 256 + n]);
    return;
  }
  int j = i - 65536;
  if (j < 24576) {
    int t = j >> 13, jj = j & 8191, n = jj >> 6, k = jj & 63;
    const float* w1 = t == 0 ? w1s : (t == 1 ? w1a : w1n);
    w1T[j] = f2bf(w1[k * 128 + n]);
    return;
  }
  j -= 24576;
  if (j < 98304) {
    int t = j >> 15, jj = j & 32767, n = jj >> 7, k = jj & 127;
    const float* w2 = t == 0 ? w2s : (t == 1 ? w2a : w2n);
    w2T[j] = f2bf(w2[k * 256 + n]);
    return;
  }
  j -= 98304;
  if (j < 196608) {
    int n = j / 768, q = j % 768, t = q >> 8, k = q & 255;
    const float* g = t == 0 ? gs : (t == 1 ? ga : gn);
    gT[j] = f2bf(g[k * 256 + n]);
  }
}

// ----------------------------- sort kernels ---------------------------------
__global__ __launch_bounds__(256) void k_hist(const int* r0, const int* r1,
                                              const int* r2, int* cnt) {
  const int t = blockIdx.z;
  const int* rcv = t == 0 ? r0 : (t == 1 ? r1 : r2);
  const int e = blockIdx.x * 256 + threadIdx.x;
  atomicAdd(&cnt[t * N_ELEC + rcv[e]], 1);
}

__global__ __launch_bounds__(256) void k_scan(const int* cnt, int* rowptr,
                                              int* cursor) {
  const int t = blockIdx.x, tid = threadIdx.x;
  __shared__ int part[256];
  const int* c = cnt + t * N_ELEC;
  int s = 0;
#pragma unroll
  for (int i = 0; i < 32; ++i) s += c[tid * 32 + i];
  part[tid] = s;
  __syncthreads();
  for (int off = 1; off < 256; off <<= 1) {
    int v = (tid >= off) ? part[tid - off] : 0;
    __syncthreads();
    part[tid] += v;
    __syncthreads();
  }
  int run = (tid == 0) ? 0 : part[tid - 1];
  int* rp = rowptr + t * RPS;
  int* cu = cursor + t * N_ELEC;
  for (int i = 0; i < 32; ++i) {
    rp[tid * 32 + i] = run;
    cu[tid * 32 + i] = run;
    run += c[tid * 32 + i];
  }
  if (tid == 255) rp[N_ELEC] = run;  // = NEDGE
}

// packed sorted-edge record: bits [16:0]=e, [29:17]=snd, [42:30]=rcv
__global__ __launch_bounds__(256) void k_place(const int* r0, const int* r1,
                                               const int* r2, const int* s0,
                                               const int* s1, const int* s2,
                                               int* cursor, u64* pk) {
  const int t = blockIdx.z;
  const int* rcv = t == 0 ? r0 : (t == 1 ? r1 : r2);
  const int* snd = t == 0 ? s0 : (t == 1 ? s1 : s2);
  const int e = blockIdx.x * 256 + threadIdx.x;
  const int rr = rcv[e];
  const int pos = atomicAdd(&cursor[t * N_ELEC + rr], 1);
  pk[t * NEDGE + pos] =
      (u64)(unsigned)e | ((u64)(unsigned)snd[e] << 17) | ((u64)(unsigned)rr << 30);
}

// ---- he = electrons @ h_w  (32-row x 256-col tiles, A staged once) ---------
// 256 blocks; wave wv owns cols wv*64..wv*64+64; acc[2][4].
// B fragments read directly from hwT (128KB, L2-resident).
__global__ __launch_bounds__(256) void k_he(const float* elec, const u16* hwT,
                                            u16* he) {
  __shared__ __align__(16) char As[2048];  // 32 x 32 bf16
  const int tid = threadIdx.x;
  const int m0 = blockIdx.x * 32;
  const int l = tid & 63, lane15 = l & 15, quad = l >> 4, wv = tid >> 6;
  const int nw = wv * 64;
  f32x4 acc[2][4];
#pragma unroll
  for (int i = 0; i < 2; ++i)
#pragma unroll
    for (int j = 0; j < 4; ++j) acc[i][j] = (f32x4){0.f, 0.f, 0.f, 0.f};
  for (int kt = 0; kt < 256; kt += 32) {
    stage_f32x32(elec + (long)m0 * 256, 256, kt, As, tid);
    __syncthreads();
    short8 af[2], bf[4];
#pragma unroll
    for (int i = 0; i < 2; ++i)
      af[i] = *(const short8*)(As + (i * 16 + lane15) * 64 + quad * 16);
#pragma unroll
    for (int i = 0; i < 4; ++i)
      bf[i] = *(const short8*)(hwT + (nw + i * 16 + lane15) * 256 + kt +
                               quad * 8);
#pragma unroll
    for (int mi = 0; mi < 2; ++mi)
#pragma unroll
      for (int ni = 0; ni < 4; ++ni)
        acc[mi][ni] = __builtin_amdgcn_mfma_f32_16x16x32_bf16(
            af[mi], bf[ni], acc[mi][ni], 0, 0, 0);
    __syncthreads();
  }
#pragma unroll
  for (int mi = 0; mi < 2; ++mi)
#pragma unroll
    for (int r = 0; r < 4; ++r) {
      const int row = m0 + mi * 16 + quad * 4 + r;
#pragma unroll
      for (int ni = 0; ni < 4; ++ni) {
        const int col = nw + ni * 16 + lane15;
        he[row * 256 + col] = f2bf(acc[mi][ni][r]);
      }
    }
}

// ---- fully fused edge kernel: EXACT R8/R9 structure (159us) + pk meta ------
// 256 threads, 4 waves; 128-edge tile; LDS 53.25KB -> 3 blocks/CU.
__global__ __launch_bounds__(256, 3) void k_edge(
    const float* d0, const float* d1, const float* d2, const float* b0,
    const float* b1p, const float* b2, const u16* w1T, const u16* w2T,
    const u16* he, const float* nucf, const u64* pk, float* z) {
  __shared__ char mid[128 * CSTR];  // 34816 B: dist halves -> mid
  __shared__ char hc[64 * CSTR];    // 17408 B: per-half He/weh tile
  __shared__ int snd_l[128], rcv_l[128];

  const int t = blockIdx.z;
  const int m0 = blockIdx.x * 128;
  const int tid = threadIdx.x;
  const float* dist = t == 0 ? d0 : (t == 1 ? d1 : d2);
  const float* bias = t == 0 ? b0 : (t == 1 ? b1p : b2);
  const u16* w1t = w1T + t * 8192;   // [128][64]
  const u16* w2t = w2T + t * 32768;  // [256][128]
  const bool is_nuc = (t == 2);
  const u64* pkt = pk + (size_t)t * NEDGE + m0;

  // tile meta: one packed load per edge (visible after first barrier)
  if (tid < 128) {
    const u64 rec = pkt[tid];
    snd_l[tid] = (int)((rec >> 17) & 0x1FFFu);
    rcv_l[tid] = (int)(rec >> 30);
  }

  // stage gathered dist rows as two K-halves [128][32] bf16 into mid[0:16K]
  int rows[4];
#pragma unroll
  for (int s = 0; s < 4; ++s)
    rows[s] = (int)(pkt[(s * 256 + tid) >> 3] & 0x1FFFFu);
#pragma unroll
  for (int j = 0; j < 2; ++j)
#pragma unroll
    for (int s = 0; s < 4; ++s) {
      const int idx = s * 256 + tid, row = idx >> 3, ch = idx & 7;
      const float4 v =
          *(const float4*)(dist + (long)rows[s] * 64 + j * 32 + ch * 4);
      uint2 p;
      p.x = pkbf(v.x, v.y);
      p.y = pkbf(v.z, v.w);
      *(uint2*)(mid + j * 8192 + row * 64 + ch * 8) = p;
    }
  bar_lds();

  const int l = tid & 63, lane15 = l & 15, quad = l >> 4, wv = tid >> 6;
  const int mw = (wv >> 1) * 64, nw = (wv & 1) * 64;

  // GEMM1: [128,64] @ [64,128] -> acc   (B = w1t direct from global, L2-hot)
  f32x4 acc[4][4];
#pragma unroll
  for (int i = 0; i < 4; ++i)
#pragma unroll
    for (int j = 0; j < 4; ++j) acc[i][j] = (f32x4){0.f, 0.f, 0.f, 0.f};
#pragma unroll
  for (int j = 0; j < 2; ++j) {
    short8 af[4], bf[4];
#pragma unroll
    for (int i = 0; i < 4; ++i) {
      af[i] = *(const short8*)(mid + j * 8192 + (mw + i * 16 + lane15) * 64 +
                               quad * 16);
      bf[i] = *(const short8*)(w1t + (nw + i * 16 + lane15) * 64 + j * 32 +
                               quad * 8);
    }
#pragma unroll
    for (int mi = 0; mi < 4; ++mi)
#pragma unroll
      for (int ni = 0; ni < 4; ++ni)
        acc[mi][ni] = __builtin_amdgcn_mfma_f32_16x16x32_bf16(
            af[mi], bf[ni], acc[mi][ni], 0, 0, 0);
  }
  bar_lds();  // all waves done reading dist halves

  // bias + SSP -> mid (272 B rows)
#pragma unroll
  for (int mi = 0; mi < 4; ++mi)
#pragma unroll
    for (int r = 0; r < 4; ++r) {
      const int row = mw + mi * 16 + quad * 4 + r;
#pragma unroll
      for (int ni = 0; ni < 4; ++ni) {
        const int col = nw + ni * 16 + lane15;
        const float x = acc[mi][ni][r] + bias[col];
        *(u16*)(mid + row * CSTR + col * 2) = f2bf(ssp_fast(x));
      }
    }
  bar_lds();  // mid visible to all waves

  for (int n0 = 0; n0 < 256; n0 += 128) {
    // GEMM2: A = mid (LDS), B = w2t cols n0.. (direct from global, L2-hot)
#pragma unroll
    for (int i = 0; i < 4; ++i)
#pragma unroll
      for (int j = 0; j < 4; ++j) acc[i][j] = (f32x4){0.f, 0.f, 0.f, 0.f};
#pragma unroll
    for (int kt = 0; kt < 128; kt += 32) {
      short8 af[4], bf[4];
#pragma unroll
      for (int i = 0; i < 4; ++i) {
        af[i] = *(const short8*)(mid + (mw + i * 16 + lane15) * CSTR + kt * 2 +
                                 quad * 16);
        bf[i] = *(const short8*)(w2t + (n0 + nw + i * 16 + lane15) * 128 + kt +
                                 quad * 8);
      }
#pragma unroll
      for (int mi = 0; mi < 4; ++mi)
#pragma unroll
        for (int ni = 0; ni < 4; ++ni)
          acc[mi][ni] = __builtin_amdgcn_mfma_f32_16x16x32_bf16(
              af[mi], bf[ni], acc[mi][ni], 0, 0, 0);
    }

    for (int h = 0; h < 2; ++h) {
      const int rbase = h * 64;
      // stage 64 src rows (cols n0..n0+128) into hc (coalesced 16 B chunks)
      if (!is_nuc) {
#pragma unroll
        for (int c = 0; c < 4; ++c) {
          const int chunk = c * 256 + tid;  // 1024 x 16 B
          const int row = chunk >> 4, off = chunk & 15;
          const uint4 v =
              *(const uint4*)((const char*)he +
                              (size_t)snd_l[rbase + row] * 512 + n0 * 2 +
                              off * 16);
          *(uint4*)(hc + row * CSTR + off * 16) = v;
        }
      } else {
#pragma unroll
        for (int c = 0; c < 4; ++c) {
          const int chunk = c * 256 + tid;
          const int row = chunk >> 4, off = chunk & 15;
          const char* src = (const char*)nucf +
                            (size_t)snd_l[rbase + row] * 1024 + n0 * 4 +
                            off * 32;
          const float4 a = *(const float4*)src;
          const float4 b = *(const float4*)(src + 16);
          uint4 p;
          p.x = pkbf(a.x, a.y);
          p.y = pkbf(a.z, a.w);
          p.z = pkbf(b.x, b.y);
          p.w = pkbf(b.z, b.w);
          *(uint4*)(hc + row * CSTR + off * 16) = p;
        }
      }
      bar_lds();

      // in-place multiply: waves whose fragment rows live in this half
      if ((wv >> 1) == h) {
#pragma unroll
        for (int mi = 0; mi < 4; ++mi)
#pragma unroll
          for (int r = 0; r < 4; ++r) {
            const int lrow = mi * 16 + quad * 4 + r;  // 0..63 within half
#pragma unroll
            for (int ni = 0; ni < 4; ++ni) {
              const int col = nw + ni * 16 + lane15;
              u16* p = (u16*)(hc + lrow * CSTR) + col;
              *p = f2bf(acc[mi][ni][r] * bf2f(*p));
            }
          }
      }
      bar_lds();

      // segmented reduce: wave wv owns 16 rows of the half; lane owns a col
      // pair. Fire-and-forget atomics (bar_lds never drains vmcnt).
      {
        const int cp = l;
        const int rbeg = wv * 16, rend = rbeg + 16;
        float a0 = 0.f, a1 = 0.f;
        int cur = rcv_l[rbase + rbeg];
        for (int row = rbeg; row < rend; ++row) {
          const unsigned p = *(const unsigned*)(hc + row * CSTR + cp * 4);
          a0 += __uint_as_float(p << 16);
          a1 += __uint_as_float(p & 0xffff0000u);
          const int nxt = (row + 1 < rend) ? rcv_l[rbase + row + 1] : -1;
          if (nxt != cur) {
            float* zp = z + (size_t)cur * 768 + t * 256 + n0 + cp * 2;
            unsafeAtomicAdd(zp, a0);
            unsafeAtomicAdd(zp + 1, a1);
            a0 = a1 = 0.f;
            cur = nxt;
          }
        }
      }
      bar_lds();  // hc reused next half / n0
    }
  }
}

// ---- out = electrons + bf16(z) @ gT^T  (32-row x 256-col tiles) ------------
// 256 blocks; A (z f32) staged once per K-chunk; B fragments direct from gT.
__global__ __launch_bounds__(256) void k_final(const float* z, const u16* gT,
                                               const float* elec, float* out) {
  __shared__ __align__(16) char As[2048];  // 32 x 32 bf16
  const int tid = threadIdx.x;
  const int m0 = blockIdx.x * 32;
  const int l = tid & 63, lane15 = l & 15, quad = l >> 4, wv = tid >> 6;
  const int nw = wv * 64;
  f32x4 acc[2][4];
#pragma unroll
  for (int i = 0; i < 2; ++i)
#pragma unroll
    for (int j = 0; j < 4; ++j) acc[i][j] = (f32x4){0.f, 0.f, 0.f, 0.f};
  for (int kt = 0; kt < 768; kt += 32) {
    stage_f32x32(z + (long)m0 * 768, 768, kt, As, tid);
    __syncthreads();
    short8 af[2], bf[4];
#pragma unroll
    for (int i = 0; i < 2; ++i)
      af[i] = *(const short8*)(As + (i * 16 + lane15) * 64 + quad * 16);
#pragma unroll
    for (int i = 0; i < 4; ++i)
      bf[i] = *(const short8*)(gT + (nw + i * 16 + lane15) * 768 + kt +
                               quad * 8);
#pragma unroll
    for (int mi = 0; mi < 2; ++mi)
#pragma unroll
      for (int ni = 0; ni < 4; ++ni)
        acc[mi][ni] = __builtin_amdgcn_mfma_f32_16x16x32_bf16(
            af[mi], bf[ni], acc[mi][ni], 0, 0, 0);
    __syncthreads();
  }
#pragma unroll
  for (int mi = 0; mi < 2; ++mi)
#pragma unroll
    for (int r = 0; r < 4; ++r) {
      const int row = m0 + mi * 16 + quad * 4 + r;
#pragma unroll
      for (int ni = 0; ni < 4; ++ni) {
        const int col = nw + ni * 16 + lane15;
        out[row * 256 + col] = acc[mi][ni][r] + elec[row * 256 + col];
      }
    }
}

// ---------------------------------------------------------------------------
extern "C" void kernel_launch(void* const* d_in, const int* in_sizes, int n_in,
                              void* d_out, int out_size, void* d_ws,
                              size_t ws_size, hipStream_t stream) {
  int I_dist[3], I_w1[3], I_b1[3], I_w2[3], I_g[3], I_hw;
  if (in_sizes[3] == 64 * 128) {  // setup_inputs() dict order
    for (int t = 0; t < 3; ++t) {
      I_dist[t] = 2 + t * 5 + 0;
      I_w1[t] = 2 + t * 5 + 1;
      I_b1[t] = 2 + t * 5 + 2;
      I_w2[t] = 2 + t * 5 + 3;
      I_g[t] = 2 + t * 5 + 4;
    }
    I_hw = 17;
  } else {  // reference signature order
    I_dist[0] = 2; I_dist[1] = 3; I_dist[2] = 4;
    I_w1[0] = 5;  I_b1[0] = 6;  I_w2[0] = 7;
    I_w1[1] = 8;  I_b1[1] = 9;  I_w2[1] = 10;
    I_w1[2] = 11; I_b1[2] = 12; I_w2[2] = 13;
    I_g[0] = 14; I_g[1] = 15; I_g[2] = 16;
    I_hw = 17;
  }
  const int I_snd[3] = {18, 19, 20};
  const int I_rcv[3] = {21, 22, 23};

  char* ws = (char*)d_ws;
  // workspace layout (bytes). Total ~34 MB.
  u16* he = (u16*)(ws + 0);              //   4,194,304
  u16* hwT = (u16*)(ws + 4194304);       //     131,072
  u16* w1T = (u16*)(ws + 4325376);       //      49,152
  u16* w2T = (u16*)(ws + 4374528);       //     196,608
  u16* gT = (u16*)(ws + 4571136);        //     393,216
  float* z = (float*)(ws + 4964352);     //  25,165,824
  int* cnt = (int*)(ws + 30130176);      //      98,304
  int* rowptr = (int*)(ws + 30228480);   //      99,072
  int* cursor = (int*)(ws + 30327552);   //      98,304
  u64* pk = (u64*)(ws + 30425856);       //   3,145,728

  const float* elec = (const float*)d_in[0];
  const float* nuc = (const float*)d_in[1];
  const int* s0 = (const int*)d_in[I_snd[0]];
  const int* s1 = (const int*)d_in[I_snd[1]];
  const int* s2 = (const int*)d_in[I_snd[2]];
  const int* r0 = (const int*)d_in[I_rcv[0]];
  const int* r1 = (const int*)d_in[I_rcv[1]];
  const int* r2 = (const int*)d_in[I_rcv[2]];

  // z=0 (6144) + cnt=0 (96) + weight transposes (1504) in one dispatch
  k_setup<<<7744, 256, 0, stream>>>(
      (const float*)d_in[I_hw], (const float*)d_in[I_w1[0]],
      (const float*)d_in[I_w1[1]], (const float*)d_in[I_w1[2]],
      (const float*)d_in[I_w2[0]], (const float*)d_in[I_w2[1]],
      (const float*)d_in[I_w2[2]], (const float*)d_in[I_g[0]],
      (const float*)d_in[I_g[1]], (const float*)d_in[I_g[2]], hwT, w1T, w2T,
      gT, (float4*)z, cnt);

  // counting sort by receiver, per type
  k_hist<<<dim3(NEDGE / 256, 1, 3), 256, 0, stream>>>(r0, r1, r2, cnt);
  k_scan<<<3, 256, 0, stream>>>(cnt, rowptr, cursor);
  k_place<<<dim3(NEDGE / 256, 1, 3), 256, 0, stream>>>(r0, r1, r2, s0, s1, s2,
                                                       cursor, pk);

  k_he<<<N_ELEC / 32, 256, 0, stream>>>(elec, hwT, he);

  k_edge<<<dim3(NEDGE / 128, 1, 3), 256, 0, stream>>>(
      (const float*)d_in[I_dist[0]], (const float*)d_in[I_dist[1]],
      (const float*)d_in[I_dist[2]], (const float*)d_in[I_b1[0]],
      (const float*)d_in[I_b1[1]], (const float*)d_in[I_b1[2]], w1T, w2T, he,
      nuc, pk, z);

  k_final<<<N_ELEC / 32, 256, 0, stream>>>(z, gT, elec, (float*)d_out);
}

// Round 10
// 391.980 us; speedup vs baseline: 1.1874x; 1.0230x over previous
//
#include <hip/hip_runtime.h>
#include <stdint.h>

// ---------------------------------------------------------------------------
// SchNetLayer on MI355X (gfx950).
// I/O: float tensors f32, indices int32. Internal: bf16 MFMA.
//
// R2: atomic scatter = atomic-rate bound -> counting sort.
// R3: libm softplus -> native v_exp/v_log.
// R4/R5: fuse gather/MLP/multiply/reduce into k_edge.
// R6-R8: LDS/occupancy tuning -> 128-edge tile, 3 blocks/CU, 159us.
// R9-R16: k_edge redesigns (occupancy/atomics/barriers/LDS-round-trip) all
//      lose to R8's 159us. R8 = local optimum. k_edge frozen.
// R17: retiled k_he/k_final for HBM reuse: NEUTRAL (403->401). z/he fit in
//      L3/L2 -> the 4x A re-reads were cache hits. Tail (242us, invariant
//      across 9 rounds) is NOT HBM traffic. Remaining candidates: serial
//      phase chains in small GEMMs (k_final: 24 x {stage,bar,MFMA,bar} at
//      1 block/CU = pure latency chain) + 7 dispatch boundaries.
// R18: single-phase GEMM tails + dispatch fusion. k_final/k_he stage the
//      whole A-strip once (49.7KB/16.9KB padded LDS), one barrier, then
//      all MFMA K-steps barrier-free (B per-fragment from L2). k_hist
//      folded into k_setup (cnt pre-zeroed via hipMemsetAsync node);
//      k_he fused into k_place dispatch. 7 kernels -> 5 + 1 memset.
//
// Pipeline:
//   memset(cnt=0)
//   k_setup: z=0, weight transposes, edge histogram (one dispatch)
//   k_scan : per-type exclusive scan -> rowptr/cursor
//   k_place_he: blocks<1536 counting-sort place (packed u64 rec);
//               blocks>=1536 he = bf16(elec)@h_w (32x256 single-phase)
//   k_edge : per 128-edge tile (sorted): mid=SSP(dist[perm]@w1+b1) in LDS;
//            for n0 in {0,128}: we=mid@w2; for half in {0,1}: stage 64
//            src rows, weh=we*src, 16-row-strip segmented reduce -> z atomics
//   k_final: out = elec + bf16(z)@gT^T (32x256 single-phase)
// ---------------------------------------------------------------------------

#define N_ELEC 8192
#define N_NUC  512
#define EMB    256
#define KER    256
#define DF     64
#define MID    128
#define NEDGE  131072
#define RPS    8256   // rowptr per-type stride (ints)
#define CSTR   272    // LDS row stride bytes for 128-col u16 tiles (+16 pad)
#define ASTR_HE 528   // he A-tile row stride bytes (256 bf16 + 8 pad)
#define ASTR_FN 1552  // k_final A-tile row stride bytes (768 bf16 + 8 pad)

using u16 = unsigned short;
using u64 = unsigned long long;
typedef short short8 __attribute__((ext_vector_type(8)));
typedef float f32x4 __attribute__((ext_vector_type(4)));

__device__ __forceinline__ float bf2f(u16 h) {
  return __uint_as_float(((unsigned)h) << 16);
}
__device__ __forceinline__ u16 f2bf(float f) {
  unsigned u = __float_as_uint(f);
  return (u16)((u + 0x7FFFu + ((u >> 16) & 1u)) >> 16);  // RNE
}
__device__ __forceinline__ unsigned pkbf(float a, float b) {
  return ((unsigned)f2bf(b) << 16) | (unsigned)f2bf(a);
}
// fast shifted softplus: log(0.5 e^x + 0.5), stable, native v_exp/v_log.
__device__ __forceinline__ float ssp_fast(float x) {
  const float e = __expf(-fabsf(x));
  return fmaxf(x, 0.f) + __logf(fmaf(0.5f, e, 0.5f));
}

// LDS-only workgroup barrier: no vmcnt drain; cross-wave deps in k_edge are
// LDS-only; z atomics fire-and-forget. sched_barrier(0) per rule #18.
__device__ __forceinline__ void bar_lds() {
  __builtin_amdgcn_sched_barrier(0);
  asm volatile("s_waitcnt lgkmcnt(0)" ::: "memory");
  __builtin_amdgcn_s_barrier();
  __builtin_amdgcn_sched_barrier(0);
}

// ---- setup: z=0, weight transposes, histogram (single dispatch) ------------
// cnt must be zeroed by a preceding memset node. Blocks:
//   [0,6144)      z = 0
//   [6144,7648)   transposes: hwT/w1T/w2T/gT
//   [7648,9184)   histogram: cnt[t][rcv] atomics
__global__ __launch_bounds__(256) void k_setup(
    const float* h_w, const float* w1s, const float* w1a, const float* w1n,
    const float* w2s, const float* w2a, const float* w2n, const float* gs,
    const float* ga, const float* gn, const int* r0, const int* r1,
    const int* r2, u16* hwT, u16* w1T, u16* w2T, u16* gT, float4* z,
    int* cnt) {
  const int b = blockIdx.x;
  if (b < 6144) {
    z[b * 256 + threadIdx.x] = (float4){0.f, 0.f, 0.f, 0.f};
    return;
  }
  if (b >= 7648) {
    const int eb = b - 7648;
    const int t = eb >> 9;
    const int* rcv = t == 0 ? r0 : (t == 1 ? r1 : r2);
    const int e = ((eb & 511) << 8) + threadIdx.x;
    atomicAdd(&cnt[t * N_ELEC + rcv[e]], 1);
    return;
  }
  int i = (b - 6144) * 256 + threadIdx.x;
  if (i < 65536) {
    int n = i >> 8, k = i & 255;
    hwT[i] = f2bf(h_w[k * 256 + n]);
    return;
  }
  int j = i - 65536;
  if (j < 24576) {
    int t = j >> 13, jj = j & 8191, n = jj >> 6, k = jj & 63;
    const float* w1 = t == 0 ? w1s : (t == 1 ? w1a : w1n);
    w1T[j] = f2bf(w1[k * 128 + n]);
    return;
  }
  j -= 24576;
  if (j < 98304) {
    int t = j >> 15, jj = j & 32767, n = jj >> 7, k = jj & 127;
    const float* w2 = t == 0 ? w2s : (t == 1 ? w2a : w2n);
    w2T[j] = f2bf(w2[k * 256 + n]);
    return;
  }
  j -= 98304;
  if (j < 196608) {
    int n = j / 768, q = j % 768, t = q >> 8, k = q & 255;
    const float* g = t == 0 ? gs : (t == 1 ? ga : gn);
    gT[j] = f2bf(g[k * 256 + n]);
  }
}

__global__ __launch_bounds__(256) void k_scan(const int* cnt, int* rowptr,
                                              int* cursor) {
  const int t = blockIdx.x, tid = threadIdx.x;
  __shared__ int part[256];
  const int* c = cnt + t * N_ELEC;
  int s = 0;
#pragma unroll
  for (int i = 0; i < 32; ++i) s += c[tid * 32 + i];
  part[tid] = s;
  __syncthreads();
  for (int off = 1; off < 256; off <<= 1) {
    int v = (tid >= off) ? part[tid - off] : 0;
    __syncthreads();
    part[tid] += v;
    __syncthreads();
  }
  int run = (tid == 0) ? 0 : part[tid - 1];
  int* rp = rowptr + t * RPS;
  int* cu = cursor + t * N_ELEC;
  for (int i = 0; i < 32; ++i) {
    rp[tid * 32 + i] = run;
    cu[tid * 32 + i] = run;
    run += c[tid * 32 + i];
  }
  if (tid == 255) rp[N_ELEC] = run;  // = NEDGE
}

// ---- fused place + he dispatch ---------------------------------------------
// blocks [0,1536): counting-sort place, packed u64 rec (e|snd|rcv)
// blocks [1536,1792): he = bf16(elec) @ h_w, 32-row x 256-col single-phase
__global__ __launch_bounds__(256) void k_place_he(
    const int* r0, const int* r1, const int* r2, const int* s0, const int* s1,
    const int* s2, int* cursor, u64* pk, const float* elec, const u16* hwT,
    u16* he) {
  __shared__ __align__(16) char As[32 * ASTR_HE];  // 16896 B (he path only)
  const int bid = blockIdx.x, tid = threadIdx.x;
  if (bid < 1536) {
    const int t = bid >> 9;
    const int* rcv = t == 0 ? r0 : (t == 1 ? r1 : r2);
    const int* snd = t == 0 ? s0 : (t == 1 ? s1 : s2);
    const int e = ((bid & 511) << 8) + tid;
    const int rr = rcv[e];
    const int pos = atomicAdd(&cursor[t * N_ELEC + rr], 1);
    pk[t * NEDGE + pos] = (u64)(unsigned)e | ((u64)(unsigned)snd[e] << 17) |
                          ((u64)(unsigned)rr << 30);
    return;
  }
  const int m0 = (bid - 1536) * 32;
  // stage A once: 32 rows x 256 f32 -> bf16 (4096 float2, 16/thread)
#pragma unroll
  for (int i = 0; i < 16; ++i) {
    const int idx = i * 256 + tid;
    const int row = idx >> 7, cp = idx & 127;
    const float2 v = *(const float2*)(elec + (long)(m0 + row) * 256 + cp * 2);
    *(unsigned*)(As + row * ASTR_HE + cp * 4) = pkbf(v.x, v.y);
  }
  __syncthreads();
  const int l = tid & 63, lane15 = l & 15, quad = l >> 4, wv = tid >> 6;
  const int nw = wv * 64;
  f32x4 acc[2][4];
#pragma unroll
  for (int i = 0; i < 2; ++i)
#pragma unroll
    for (int j = 0; j < 4; ++j) acc[i][j] = (f32x4){0.f, 0.f, 0.f, 0.f};
  for (int kt = 0; kt < 256; kt += 32) {
    short8 af[2], bf[4];
#pragma unroll
    for (int i = 0; i < 2; ++i)
      af[i] = *(const short8*)(As + (i * 16 + lane15) * ASTR_HE + kt * 2 +
                               quad * 16);
#pragma unroll
    for (int i = 0; i < 4; ++i)
      bf[i] = *(const short8*)(hwT + (nw + i * 16 + lane15) * 256 + kt +
                               quad * 8);
#pragma unroll
    for (int mi = 0; mi < 2; ++mi)
#pragma unroll
      for (int ni = 0; ni < 4; ++ni)
        acc[mi][ni] = __builtin_amdgcn_mfma_f32_16x16x32_bf16(
            af[mi], bf[ni], acc[mi][ni], 0, 0, 0);
  }
#pragma unroll
  for (int mi = 0; mi < 2; ++mi)
#pragma unroll
    for (int r = 0; r < 4; ++r) {
      const int row = m0 + mi * 16 + quad * 4 + r;
#pragma unroll
      for (int ni = 0; ni < 4; ++ni) {
        const int col = nw + ni * 16 + lane15;
        he[row * 256 + col] = f2bf(acc[mi][ni][r]);
      }
    }
}

// ---- fully fused edge kernel: EXACT R8/R9 structure (159us, frozen) --------
// 256 threads, 4 waves; 128-edge tile; LDS 53.25KB -> 3 blocks/CU.
__global__ __launch_bounds__(256, 3) void k_edge(
    const float* d0, const float* d1, const float* d2, const float* b0,
    const float* b1p, const float* b2, const u16* w1T, const u16* w2T,
    const u16* he, const float* nucf, const u64* pk, float* z) {
  __shared__ char mid[128 * CSTR];  // 34816 B: dist halves -> mid
  __shared__ char hc[64 * CSTR];    // 17408 B: per-half He/weh tile
  __shared__ int snd_l[128], rcv_l[128];

  const int t = blockIdx.z;
  const int m0 = blockIdx.x * 128;
  const int tid = threadIdx.x;
  const float* dist = t == 0 ? d0 : (t == 1 ? d1 : d2);
  const float* bias = t == 0 ? b0 : (t == 1 ? b1p : b2);
  const u16* w1t = w1T + t * 8192;   // [128][64]
  const u16* w2t = w2T + t * 32768;  // [256][128]
  const bool is_nuc = (t == 2);
  const u64* pkt = pk + (size_t)t * NEDGE + m0;

  // tile meta: one packed load per edge (visible after first barrier)
  if (tid < 128) {
    const u64 rec = pkt[tid];
    snd_l[tid] = (int)((rec >> 17) & 0x1FFFu);
    rcv_l[tid] = (int)(rec >> 30);
  }

  // stage gathered dist rows as two K-halves [128][32] bf16 into mid[0:16K]
  int rows[4];
#pragma unroll
  for (int s = 0; s < 4; ++s)
    rows[s] = (int)(pkt[(s * 256 + tid) >> 3] & 0x1FFFFu);
#pragma unroll
  for (int j = 0; j < 2; ++j)
#pragma unroll
    for (int s = 0; s < 4; ++s) {
      const int idx = s * 256 + tid, row = idx >> 3, ch = idx & 7;
      const float4 v =
          *(const float4*)(dist + (long)rows[s] * 64 + j * 32 + ch * 4);
      uint2 p;
      p.x = pkbf(v.x, v.y);
      p.y = pkbf(v.z, v.w);
      *(uint2*)(mid + j * 8192 + row * 64 + ch * 8) = p;
    }
  bar_lds();

  const int l = tid & 63, lane15 = l & 15, quad = l >> 4, wv = tid >> 6;
  const int mw = (wv >> 1) * 64, nw = (wv & 1) * 64;

  // GEMM1: [128,64] @ [64,128] -> acc   (B = w1t direct from global, L2-hot)
  f32x4 acc[4][4];
#pragma unroll
  for (int i = 0; i < 4; ++i)
#pragma unroll
    for (int j = 0; j < 4; ++j) acc[i][j] = (f32x4){0.f, 0.f, 0.f, 0.f};
#pragma unroll
  for (int j = 0; j < 2; ++j) {
    short8 af[4], bf[4];
#pragma unroll
    for (int i = 0; i < 4; ++i) {
      af[i] = *(const short8*)(mid + j * 8192 + (mw + i * 16 + lane15) * 64 +
                               quad * 16);
      bf[i] = *(const short8*)(w1t + (nw + i * 16 + lane15) * 64 + j * 32 +
                               quad * 8);
    }
#pragma unroll
    for (int mi = 0; mi < 4; ++mi)
#pragma unroll
      for (int ni = 0; ni < 4; ++ni)
        acc[mi][ni] = __builtin_amdgcn_mfma_f32_16x16x32_bf16(
            af[mi], bf[ni], acc[mi][ni], 0, 0, 0);
  }
  bar_lds();  // all waves done reading dist halves

  // bias + SSP -> mid (272 B rows)
#pragma unroll
  for (int mi = 0; mi < 4; ++mi)
#pragma unroll
    for (int r = 0; r < 4; ++r) {
      const int row = mw + mi * 16 + quad * 4 + r;
#pragma unroll
      for (int ni = 0; ni < 4; ++ni) {
        const int col = nw + ni * 16 + lane15;
        const float x = acc[mi][ni][r] + bias[col];
        *(u16*)(mid + row * CSTR + col * 2) = f2bf(ssp_fast(x));
      }
    }
  bar_lds();  // mid visible to all waves

  for (int n0 = 0; n0 < 256; n0 += 128) {
    // GEMM2: A = mid (LDS), B = w2t cols n0.. (direct from global, L2-hot)
#pragma unroll
    for (int i = 0; i < 4; ++i)
#pragma unroll
      for (int j = 0; j < 4; ++j) acc[i][j] = (f32x4){0.f, 0.f, 0.f, 0.f};
#pragma unroll
    for (int kt = 0; kt < 128; kt += 32) {
      short8 af[4], bf[4];
#pragma unroll
      for (int i = 0; i < 4; ++i) {
        af[i] = *(const short8*)(mid + (mw + i * 16 + lane15) * CSTR + kt * 2 +
                                 quad * 16);
        bf[i] = *(const short8*)(w2t + (n0 + nw + i * 16 + lane15) * 128 + kt +
                                 quad * 8);
      }
#pragma unroll
      for (int mi = 0; mi < 4; ++mi)
#pragma unroll
        for (int ni = 0; ni < 4; ++ni)
          acc[mi][ni] = __builtin_amdgcn_mfma_f32_16x16x32_bf16(
              af[mi], bf[ni], acc[mi][ni], 0, 0, 0);
    }

    for (int h = 0; h < 2; ++h) {
      const int rbase = h * 64;
      // stage 64 src rows (cols n0..n0+128) into hc (coalesced 16 B chunks)
      if (!is_nuc) {
#pragma unroll
        for (int c = 0; c < 4; ++c) {
          const int chunk = c * 256 + tid;  // 1024 x 16 B
          const int row = chunk >> 4, off = chunk & 15;
          const uint4 v =
              *(const uint4*)((const char*)he +
                              (size_t)snd_l[rbase + row] * 512 + n0 * 2 +
                              off * 16);
          *(uint4*)(hc + row * CSTR + off * 16) = v;
        }
      } else {
#pragma unroll
        for (int c = 0; c < 4; ++c) {
          const int chunk = c * 256 + tid;
          const int row = chunk >> 4, off = chunk & 15;
          const char* src = (const char*)nucf +
                            (size_t)snd_l[rbase + row] * 1024 + n0 * 4 +
                            off * 32;
          const float4 a = *(const float4*)src;
          const float4 b = *(const float4*)(src + 16);
          uint4 p;
          p.x = pkbf(a.x, a.y);
          p.y = pkbf(a.z, a.w);
          p.z = pkbf(b.x, b.y);
          p.w = pkbf(b.z, b.w);
          *(uint4*)(hc + row * CSTR + off * 16) = p;
        }
      }
      bar_lds();

      // in-place multiply: waves whose fragment rows live in this half
      if ((wv >> 1) == h) {
#pragma unroll
        for (int mi = 0; mi < 4; ++mi)
#pragma unroll
          for (int r = 0; r < 4; ++r) {
            const int lrow = mi * 16 + quad * 4 + r;  // 0..63 within half
#pragma unroll
            for (int ni = 0; ni < 4; ++ni) {
              const int col = nw + ni * 16 + lane15;
              u16* p = (u16*)(hc + lrow * CSTR) + col;
              *p = f2bf(acc[mi][ni][r] * bf2f(*p));
            }
          }
      }
      bar_lds();

      // segmented reduce: wave wv owns 16 rows of the half; lane owns a col
      // pair. Fire-and-forget atomics (bar_lds never drains vmcnt).
      {
        const int cp = l;
        const int rbeg = wv * 16, rend = rbeg + 16;
        float a0 = 0.f, a1 = 0.f;
        int cur = rcv_l[rbase + rbeg];
        for (int row = rbeg; row < rend; ++row) {
          const unsigned p = *(const unsigned*)(hc + row * CSTR + cp * 4);
          a0 += __uint_as_float(p << 16);
          a1 += __uint_as_float(p & 0xffff0000u);
          const int nxt = (row + 1 < rend) ? rcv_l[rbase + row + 1] : -1;
          if (nxt != cur) {
            float* zp = z + (size_t)cur * 768 + t * 256 + n0 + cp * 2;
            unsafeAtomicAdd(zp, a0);
            unsafeAtomicAdd(zp + 1, a1);
            a0 = a1 = 0.f;
            cur = nxt;
          }
        }
      }
      bar_lds();  // hc reused next half / n0
    }
  }
}

// ---- out = elec + bf16(z) @ gT^T  (32x256 tiles, single-phase) -------------
// 256 blocks. A (32x768 f32 z-strip) staged ONCE to padded LDS; one barrier;
// all 24 K-steps barrier-free (B per-fragment from L2-resident gT).
__global__ __launch_bounds__(256) void k_final(const float* z, const u16* gT,
                                               const float* elec, float* out) {
  __shared__ __align__(16) char As[32 * ASTR_FN];  // 49664 B
  const int tid = threadIdx.x;
  const int m0 = blockIdx.x * 32;
  // stage A once: 32 rows x 768 f32 = 6144 float4, 24/thread, coalesced
#pragma unroll
  for (int i = 0; i < 24; ++i) {
    const int idx = i * 256 + tid;  // 0..6143
    const int row = idx / 192, q = idx % 192;
    const float4 v = *(const float4*)(z + (long)(m0 + row) * 768 + q * 4);
    uint2 p;
    p.x = pkbf(v.x, v.y);
    p.y = pkbf(v.z, v.w);
    *(uint2*)(As + row * ASTR_FN + q * 8) = p;
  }
  __syncthreads();
  const int l = tid & 63, lane15 = l & 15, quad = l >> 4, wv = tid >> 6;
  const int nw = wv * 64;
  f32x4 acc[2][4];
#pragma unroll
  for (int i = 0; i < 2; ++i)
#pragma unroll
    for (int j = 0; j < 4; ++j) acc[i][j] = (f32x4){0.f, 0.f, 0.f, 0.f};
  for (int kt = 0; kt < 768; kt += 32) {
    short8 af[2], bf[4];
#pragma unroll
    for (int i = 0; i < 2; ++i)
      af[i] = *(const short8*)(As + (i * 16 + lane15) * ASTR_FN + kt * 2 +
                               quad * 16);
#pragma unroll
    for (int i = 0; i < 4; ++i)
      bf[i] = *(const short8*)(gT + (nw + i * 16 + lane15) * 768 + kt +
                               quad * 8);
#pragma unroll
    for (int mi = 0; mi < 2; ++mi)
#pragma unroll
      for (int ni = 0; ni < 4; ++ni)
        acc[mi][ni] = __builtin_amdgcn_mfma_f32_16x16x32_bf16(
            af[mi], bf[ni], acc[mi][ni], 0, 0, 0);
  }
#pragma unroll
  for (int mi = 0; mi < 2; ++mi)
#pragma unroll
    for (int r = 0; r < 4; ++r) {
      const int row = m0 + mi * 16 + quad * 4 + r;
#pragma unroll
      for (int ni = 0; ni < 4; ++ni) {
        const int col = nw + ni * 16 + lane15;
        out[row * 256 + col] = acc[mi][ni][r] + elec[row * 256 + col];
      }
    }
}

// ---------------------------------------------------------------------------
extern "C" void kernel_launch(void* const* d_in, const int* in_sizes, int n_in,
                              void* d_out, int out_size, void* d_ws,
                              size_t ws_size, hipStream_t stream) {
  int I_dist[3], I_w1[3], I_b1[3], I_w2[3], I_g[3], I_hw;
  if (in_sizes[3] == 64 * 128) {  // setup_inputs() dict order
    for (int t = 0; t < 3; ++t) {
      I_dist[t] = 2 + t * 5 + 0;
      I_w1[t] = 2 + t * 5 + 1;
      I_b1[t] = 2 + t * 5 + 2;
      I_w2[t] = 2 + t * 5 + 3;
      I_g[t] = 2 + t * 5 + 4;
    }
    I_hw = 17;
  } else {  // reference signature order
    I_dist[0] = 2; I_dist[1] = 3; I_dist[2] = 4;
    I_w1[0] = 5;  I_b1[0] = 6;  I_w2[0] = 7;
    I_w1[1] = 8;  I_b1[1] = 9;  I_w2[1] = 10;
    I_w1[2] = 11; I_b1[2] = 12; I_w2[2] = 13;
    I_g[0] = 14; I_g[1] = 15; I_g[2] = 16;
    I_hw = 17;
  }
  const int I_snd[3] = {18, 19, 20};
  const int I_rcv[3] = {21, 22, 23};

  char* ws = (char*)d_ws;
  // workspace layout (bytes). Total ~34 MB.
  u16* he = (u16*)(ws + 0);              //   4,194,304
  u16* hwT = (u16*)(ws + 4194304);       //     131,072
  u16* w1T = (u16*)(ws + 4325376);       //      49,152
  u16* w2T = (u16*)(ws + 4374528);       //     196,608
  u16* gT = (u16*)(ws + 4571136);        //     393,216
  float* z = (float*)(ws + 4964352);     //  25,165,824
  int* cnt = (int*)(ws + 30130176);      //      98,304
  int* rowptr = (int*)(ws + 30228480);   //      99,072
  int* cursor = (int*)(ws + 30327552);   //      98,304
  u64* pk = (u64*)(ws + 30425856);       //   3,145,728

  const float* elec = (const float*)d_in[0];
  const float* nuc = (const float*)d_in[1];
  const int* s0 = (const int*)d_in[I_snd[0]];
  const int* s1 = (const int*)d_in[I_snd[1]];
  const int* s2 = (const int*)d_in[I_snd[2]];
  const int* r0 = (const int*)d_in[I_rcv[0]];
  const int* r1 = (const int*)d_in[I_rcv[1]];
  const int* r2 = (const int*)d_in[I_rcv[2]];

  // cnt = 0 (memset node; k_setup's histogram blocks atomically build on it)
  hipMemsetAsync(cnt, 0, 98304, stream);

  // z=0 (6144) + transposes (1504) + histogram (1536) in one dispatch
  k_setup<<<9184, 256, 0, stream>>>(
      (const float*)d_in[I_hw], (const float*)d_in[I_w1[0]],
      (const float*)d_in[I_w1[1]], (const float*)d_in[I_w1[2]],
      (const float*)d_in[I_w2[0]], (const float*)d_in[I_w2[1]],
      (const float*)d_in[I_w2[2]], (const float*)d_in[I_g[0]],
      (const float*)d_in[I_g[1]], (const float*)d_in[I_g[2]], r0, r1, r2,
      hwT, w1T, w2T, gT, (float4*)z, cnt);

  k_scan<<<3, 256, 0, stream>>>(cnt, rowptr, cursor);

  // place (1536 blocks) + he (256 blocks) in one dispatch
  k_place_he<<<1792, 256, 0, stream>>>(r0, r1, r2, s0, s1, s2, cursor, pk,
                                       elec, hwT, he);

  k_edge<<<dim3(NEDGE / 128, 1, 3), 256, 0, stream>>>(
      (const float*)d_in[I_dist[0]], (const float*)d_in[I_dist[1]],
      (const float*)d_in[I_dist[2]], (const float*)d_in[I_b1[0]],
      (const float*)d_in[I_b1[1]], (const float*)d_in[I_b1[2]], w1T, w2T, he,
      nuc, pk, z);

  k_final<<<N_ELEC / 32, 256, 0, stream>>>(z, gT, elec, (float*)d_out);
}

// Round 11
// 391.597 us; speedup vs baseline: 1.1886x; 1.0010x over previous
//
#include <hip/hip_runtime.h>
#include <stdint.h>

// ---------------------------------------------------------------------------
// SchNetLayer on MI355X (gfx950).
// I/O: float tensors f32, indices int32. Internal: bf16 MFMA.
//
// R2: atomic scatter = atomic-rate bound -> counting sort.
// R3: libm softplus -> native v_exp/v_log.
// R4/R5: fuse gather/MLP/multiply/reduce into k_edge.
// R6-R8: LDS/occupancy tuning -> 128-edge tile, 3 blocks/CU, 159us.
// R9-R16: k_edge redesigns (occupancy/atomics/barriers/LDS-round-trip) all
//      lose to R8's 159us. R8 = local optimum. k_edge frozen.
// R17: k_he/k_final HBM retile: NEUTRAL (z/he are L2/L3-resident; the 4x
//      A re-reads were cache hits, not HBM).
// R18: single-phase GEMM tails + dispatch fusion (7 kernels -> 5+memset):
//      401 -> 392us. Calibrates node bubble ~3-4us; old k_final's 24-phase
//      chain was only worth a few us. Tail = sum of small kernels
//      (setup~10, scan~10, place_he~25, final~35) + bubbles. No big target.
// R19: T5 s_setprio(1) around k_edge MFMA clusters. 3 independent blocks/CU
//      at different phases = the attn-style role-diversity regime where
//      setprio paid +4-7% (m191), unlike the lockstep-GEMM null (m190).
//      Zero-cost if null. Everything else frozen.
//
// Pipeline:
//   memset(cnt=0)
//   k_setup: z=0, weight transposes, edge histogram (one dispatch)
//   k_scan : per-type exclusive scan -> rowptr/cursor
//   k_place_he: blocks<1536 counting-sort place (packed u64 rec);
//               blocks>=1536 he = bf16(elec)@h_w (32x256 single-phase)
//   k_edge : per 128-edge tile (sorted): mid=SSP(dist[perm]@w1+b1) in LDS;
//            for n0 in {0,128}: we=mid@w2; for half in {0,1}: stage 64
//            src rows, weh=we*src, 16-row-strip segmented reduce -> z atomics
//   k_final: out = elec + bf16(z)@gT^T (32x256 single-phase)
// ---------------------------------------------------------------------------

#define N_ELEC 8192
#define N_NUC  512
#define EMB    256
#define KER    256
#define DF     64
#define MID    128
#define NEDGE  131072
#define RPS    8256   // rowptr per-type stride (ints)
#define CSTR   272    // LDS row stride bytes for 128-col u16 tiles (+16 pad)
#define ASTR_HE 528   // he A-tile row stride bytes (256 bf16 + 8 pad)
#define ASTR_FN 1552  // k_final A-tile row stride bytes (768 bf16 + 8 pad)

using u16 = unsigned short;
using u64 = unsigned long long;
typedef short short8 __attribute__((ext_vector_type(8)));
typedef float f32x4 __attribute__((ext_vector_type(4)));

__device__ __forceinline__ float bf2f(u16 h) {
  return __uint_as_float(((unsigned)h) << 16);
}
__device__ __forceinline__ u16 f2bf(float f) {
  unsigned u = __float_as_uint(f);
  return (u16)((u + 0x7FFFu + ((u >> 16) & 1u)) >> 16);  // RNE
}
__device__ __forceinline__ unsigned pkbf(float a, float b) {
  return ((unsigned)f2bf(b) << 16) | (unsigned)f2bf(a);
}
// fast shifted softplus: log(0.5 e^x + 0.5), stable, native v_exp/v_log.
__device__ __forceinline__ float ssp_fast(float x) {
  const float e = __expf(-fabsf(x));
  return fmaxf(x, 0.f) + __logf(fmaf(0.5f, e, 0.5f));
}

// LDS-only workgroup barrier: no vmcnt drain; cross-wave deps in k_edge are
// LDS-only; z atomics fire-and-forget. sched_barrier(0) per rule #18.
__device__ __forceinline__ void bar_lds() {
  __builtin_amdgcn_sched_barrier(0);
  asm volatile("s_waitcnt lgkmcnt(0)" ::: "memory");
  __builtin_amdgcn_s_barrier();
  __builtin_amdgcn_sched_barrier(0);
}

// ---- setup: z=0, weight transposes, histogram (single dispatch) ------------
// cnt must be zeroed by a preceding memset node. Blocks:
//   [0,6144)      z = 0
//   [6144,7648)   transposes: hwT/w1T/w2T/gT
//   [7648,9184)   histogram: cnt[t][rcv] atomics
__global__ __launch_bounds__(256) void k_setup(
    const float* h_w, const float* w1s, const float* w1a, const float* w1n,
    const float* w2s, const float* w2a, const float* w2n, const float* gs,
    const float* ga, const float* gn, const int* r0, const int* r1,
    const int* r2, u16* hwT, u16* w1T, u16* w2T, u16* gT, float4* z,
    int* cnt) {
  const int b = blockIdx.x;
  if (b < 6144) {
    z[b * 256 + threadIdx.x] = (float4){0.f, 0.f, 0.f, 0.f};
    return;
  }
  if (b >= 7648) {
    const int eb = b - 7648;
    const int t = eb >> 9;
    const int* rcv = t == 0 ? r0 : (t == 1 ? r1 : r2);
    const int e = ((eb & 511) << 8) + threadIdx.x;
    atomicAdd(&cnt[t * N_ELEC + rcv[e]], 1);
    return;
  }
  int i = (b - 6144) * 256 + threadIdx.x;
  if (i < 65536) {
    int n = i >> 8, k = i & 255;
    hwT[i] = f2bf(h_w[k * 256 + n]);
    return;
  }
  int j = i - 65536;
  if (j < 24576) {
    int t = j >> 13, jj = j & 8191, n = jj >> 6, k = jj & 63;
    const float* w1 = t == 0 ? w1s : (t == 1 ? w1a : w1n);
    w1T[j] = f2bf(w1[k * 128 + n]);
    return;
  }
  j -= 24576;
  if (j < 98304) {
    int t = j >> 15, jj = j & 32767, n = jj >> 7, k = jj & 127;
    const float* w2 = t == 0 ? w2s : (t == 1 ? w2a : w2n);
    w2T[j] = f2bf(w2[k * 256 + n]);
    return;
  }
  j -= 98304;
  if (j < 196608) {
    int n = j / 768, q = j % 768, t = q >> 8, k = q & 255;
    const float* g = t == 0 ? gs : (t == 1 ? ga : gn);
    gT[j] = f2bf(g[k * 256 + n]);
  }
}

__global__ __launch_bounds__(256) void k_scan(const int* cnt, int* rowptr,
                                              int* cursor) {
  const int t = blockIdx.x, tid = threadIdx.x;
  __shared__ int part[256];
  const int* c = cnt + t * N_ELEC;
  int s = 0;
#pragma unroll
  for (int i = 0; i < 32; ++i) s += c[tid * 32 + i];
  part[tid] = s;
  __syncthreads();
  for (int off = 1; off < 256; off <<= 1) {
    int v = (tid >= off) ? part[tid - off] : 0;
    __syncthreads();
    part[tid] += v;
    __syncthreads();
  }
  int run = (tid == 0) ? 0 : part[tid - 1];
  int* rp = rowptr + t * RPS;
  int* cu = cursor + t * N_ELEC;
  for (int i = 0; i < 32; ++i) {
    rp[tid * 32 + i] = run;
    cu[tid * 32 + i] = run;
    run += c[tid * 32 + i];
  }
  if (tid == 255) rp[N_ELEC] = run;  // = NEDGE
}

// ---- fused place + he dispatch ---------------------------------------------
// blocks [0,1536): counting-sort place, packed u64 rec (e|snd|rcv)
// blocks [1536,1792): he = bf16(elec) @ h_w, 32-row x 256-col single-phase
__global__ __launch_bounds__(256) void k_place_he(
    const int* r0, const int* r1, const int* r2, const int* s0, const int* s1,
    const int* s2, int* cursor, u64* pk, const float* elec, const u16* hwT,
    u16* he) {
  __shared__ __align__(16) char As[32 * ASTR_HE];  // 16896 B (he path only)
  const int bid = blockIdx.x, tid = threadIdx.x;
  if (bid < 1536) {
    const int t = bid >> 9;
    const int* rcv = t == 0 ? r0 : (t == 1 ? r1 : r2);
    const int* snd = t == 0 ? s0 : (t == 1 ? s1 : s2);
    const int e = ((bid & 511) << 8) + tid;
    const int rr = rcv[e];
    const int pos = atomicAdd(&cursor[t * N_ELEC + rr], 1);
    pk[t * NEDGE + pos] = (u64)(unsigned)e | ((u64)(unsigned)snd[e] << 17) |
                          ((u64)(unsigned)rr << 30);
    return;
  }
  const int m0 = (bid - 1536) * 32;
  // stage A once: 32 rows x 256 f32 -> bf16 (4096 float2, 16/thread)
#pragma unroll
  for (int i = 0; i < 16; ++i) {
    const int idx = i * 256 + tid;
    const int row = idx >> 7, cp = idx & 127;
    const float2 v = *(const float2*)(elec + (long)(m0 + row) * 256 + cp * 2);
    *(unsigned*)(As + row * ASTR_HE + cp * 4) = pkbf(v.x, v.y);
  }
  __syncthreads();
  const int l = tid & 63, lane15 = l & 15, quad = l >> 4, wv = tid >> 6;
  const int nw = wv * 64;
  f32x4 acc[2][4];
#pragma unroll
  for (int i = 0; i < 2; ++i)
#pragma unroll
    for (int j = 0; j < 4; ++j) acc[i][j] = (f32x4){0.f, 0.f, 0.f, 0.f};
  for (int kt = 0; kt < 256; kt += 32) {
    short8 af[2], bf[4];
#pragma unroll
    for (int i = 0; i < 2; ++i)
      af[i] = *(const short8*)(As + (i * 16 + lane15) * ASTR_HE + kt * 2 +
                               quad * 16);
#pragma unroll
    for (int i = 0; i < 4; ++i)
      bf[i] = *(const short8*)(hwT + (nw + i * 16 + lane15) * 256 + kt +
                               quad * 8);
#pragma unroll
    for (int mi = 0; mi < 2; ++mi)
#pragma unroll
      for (int ni = 0; ni < 4; ++ni)
        acc[mi][ni] = __builtin_amdgcn_mfma_f32_16x16x32_bf16(
            af[mi], bf[ni], acc[mi][ni], 0, 0, 0);
  }
#pragma unroll
  for (int mi = 0; mi < 2; ++mi)
#pragma unroll
    for (int r = 0; r < 4; ++r) {
      const int row = m0 + mi * 16 + quad * 4 + r;
#pragma unroll
      for (int ni = 0; ni < 4; ++ni) {
        const int col = nw + ni * 16 + lane15;
        he[row * 256 + col] = f2bf(acc[mi][ni][r]);
      }
    }
}

// ---- fully fused edge kernel: R8 structure (frozen) + T5 setprio -----------
// 256 threads, 4 waves; 128-edge tile; LDS 53.25KB -> 3 blocks/CU.
// 3 independent blocks/CU at different phases: setprio(1) around MFMA
// clusters gives MFMA-entering waves issue priority over other blocks'
// staging/reduce waves (attn-style role diversity, m191).
__global__ __launch_bounds__(256, 3) void k_edge(
    const float* d0, const float* d1, const float* d2, const float* b0,
    const float* b1p, const float* b2, const u16* w1T, const u16* w2T,
    const u16* he, const float* nucf, const u64* pk, float* z) {
  __shared__ char mid[128 * CSTR];  // 34816 B: dist halves -> mid
  __shared__ char hc[64 * CSTR];    // 17408 B: per-half He/weh tile
  __shared__ int snd_l[128], rcv_l[128];

  const int t = blockIdx.z;
  const int m0 = blockIdx.x * 128;
  const int tid = threadIdx.x;
  const float* dist = t == 0 ? d0 : (t == 1 ? d1 : d2);
  const float* bias = t == 0 ? b0 : (t == 1 ? b1p : b2);
  const u16* w1t = w1T + t * 8192;   // [128][64]
  const u16* w2t = w2T + t * 32768;  // [256][128]
  const bool is_nuc = (t == 2);
  const u64* pkt = pk + (size_t)t * NEDGE + m0;

  // tile meta: one packed load per edge (visible after first barrier)
  if (tid < 128) {
    const u64 rec = pkt[tid];
    snd_l[tid] = (int)((rec >> 17) & 0x1FFFu);
    rcv_l[tid] = (int)(rec >> 30);
  }

  // stage gathered dist rows as two K-halves [128][32] bf16 into mid[0:16K]
  int rows[4];
#pragma unroll
  for (int s = 0; s < 4; ++s)
    rows[s] = (int)(pkt[(s * 256 + tid) >> 3] & 0x1FFFFu);
#pragma unroll
  for (int j = 0; j < 2; ++j)
#pragma unroll
    for (int s = 0; s < 4; ++s) {
      const int idx = s * 256 + tid, row = idx >> 3, ch = idx & 7;
      const float4 v =
          *(const float4*)(dist + (long)rows[s] * 64 + j * 32 + ch * 4);
      uint2 p;
      p.x = pkbf(v.x, v.y);
      p.y = pkbf(v.z, v.w);
      *(uint2*)(mid + j * 8192 + row * 64 + ch * 8) = p;
    }
  bar_lds();

  const int l = tid & 63, lane15 = l & 15, quad = l >> 4, wv = tid >> 6;
  const int mw = (wv >> 1) * 64, nw = (wv & 1) * 64;

  // GEMM1: [128,64] @ [64,128] -> acc   (B = w1t direct from global, L2-hot)
  f32x4 acc[4][4];
#pragma unroll
  for (int i = 0; i < 4; ++i)
#pragma unroll
    for (int j = 0; j < 4; ++j) acc[i][j] = (f32x4){0.f, 0.f, 0.f, 0.f};
#pragma unroll
  for (int j = 0; j < 2; ++j) {
    short8 af[4], bf[4];
#pragma unroll
    for (int i = 0; i < 4; ++i) {
      af[i] = *(const short8*)(mid + j * 8192 + (mw + i * 16 + lane15) * 64 +
                               quad * 16);
      bf[i] = *(const short8*)(w1t + (nw + i * 16 + lane15) * 64 + j * 32 +
                               quad * 8);
    }
    __builtin_amdgcn_s_setprio(1);
#pragma unroll
    for (int mi = 0; mi < 4; ++mi)
#pragma unroll
      for (int ni = 0; ni < 4; ++ni)
        acc[mi][ni] = __builtin_amdgcn_mfma_f32_16x16x32_bf16(
            af[mi], bf[ni], acc[mi][ni], 0, 0, 0);
    __builtin_amdgcn_s_setprio(0);
  }
  bar_lds();  // all waves done reading dist halves

  // bias + SSP -> mid (272 B rows)
#pragma unroll
  for (int mi = 0; mi < 4; ++mi)
#pragma unroll
    for (int r = 0; r < 4; ++r) {
      const int row = mw + mi * 16 + quad * 4 + r;
#pragma unroll
      for (int ni = 0; ni < 4; ++ni) {
        const int col = nw + ni * 16 + lane15;
        const float x = acc[mi][ni][r] + bias[col];
        *(u16*)(mid + row * CSTR + col * 2) = f2bf(ssp_fast(x));
      }
    }
  bar_lds();  // mid visible to all waves

  for (int n0 = 0; n0 < 256; n0 += 128) {
    // GEMM2: A = mid (LDS), B = w2t cols n0.. (direct from global, L2-hot)
#pragma unroll
    for (int i = 0; i < 4; ++i)
#pragma unroll
      for (int j = 0; j < 4; ++j) acc[i][j] = (f32x4){0.f, 0.f, 0.f, 0.f};
#pragma unroll
    for (int kt = 0; kt < 128; kt += 32) {
      short8 af[4], bf[4];
#pragma unroll
      for (int i = 0; i < 4; ++i) {
        af[i] = *(const short8*)(mid + (mw + i * 16 + lane15) * CSTR + kt * 2 +
                                 quad * 16);
        bf[i] = *(const short8*)(w2t + (n0 + nw + i * 16 + lane15) * 128 + kt +
                                 quad * 8);
      }
      __builtin_amdgcn_s_setprio(1);
#pragma unroll
      for (int mi = 0; mi < 4; ++mi)
#pragma unroll
        for (int ni = 0; ni < 4; ++ni)
          acc[mi][ni] = __builtin_amdgcn_mfma_f32_16x16x32_bf16(
              af[mi], bf[ni], acc[mi][ni], 0, 0, 0);
      __builtin_amdgcn_s_setprio(0);
    }

    for (int h = 0; h < 2; ++h) {
      const int rbase = h * 64;
      // stage 64 src rows (cols n0..n0+128) into hc (coalesced 16 B chunks)
      if (!is_nuc) {
#pragma unroll
        for (int c = 0; c < 4; ++c) {
          const int chunk = c * 256 + tid;  // 1024 x 16 B
          const int row = chunk >> 4, off = chunk & 15;
          const uint4 v =
              *(const uint4*)((const char*)he +
                              (size_t)snd_l[rbase + row] * 512 + n0 * 2 +
                              off * 16);
          *(uint4*)(hc + row * CSTR + off * 16) = v;
        }
      } else {
#pragma unroll
        for (int c = 0; c < 4; ++c) {
          const int chunk = c * 256 + tid;
          const int row = chunk >> 4, off = chunk & 15;
          const char* src = (const char*)nucf +
                            (size_t)snd_l[rbase + row] * 1024 + n0 * 4 +
                            off * 32;
          const float4 a = *(const float4*)src;
          const float4 b = *(const float4*)(src + 16);
          uint4 p;
          p.x = pkbf(a.x, a.y);
          p.y = pkbf(a.z, a.w);
          p.z = pkbf(b.x, b.y);
          p.w = pkbf(b.z, b.w);
          *(uint4*)(hc + row * CSTR + off * 16) = p;
        }
      }
      bar_lds();

      // in-place multiply: waves whose fragment rows live in this half
      if ((wv >> 1) == h) {
#pragma unroll
        for (int mi = 0; mi < 4; ++mi)
#pragma unroll
          for (int r = 0; r < 4; ++r) {
            const int lrow = mi * 16 + quad * 4 + r;  // 0..63 within half
#pragma unroll
            for (int ni = 0; ni < 4; ++ni) {
              const int col = nw + ni * 16 + lane15;
              u16* p = (u16*)(hc + lrow * CSTR) + col;
              *p = f2bf(acc[mi][ni][r] * bf2f(*p));
            }
          }
      }
      bar_lds();

      // segmented reduce: wave wv owns 16 rows of the half; lane owns a col
      // pair. Fire-and-forget atomics (bar_lds never drains vmcnt).
      {
        const int cp = l;
        const int rbeg = wv * 16, rend = rbeg + 16;
        float a0 = 0.f, a1 = 0.f;
        int cur = rcv_l[rbase + rbeg];
        for (int row = rbeg; row < rend; ++row) {
          const unsigned p = *(const unsigned*)(hc + row * CSTR + cp * 4);
          a0 += __uint_as_float(p << 16);
          a1 += __uint_as_float(p & 0xffff0000u);
          const int nxt = (row + 1 < rend) ? rcv_l[rbase + row + 1] : -1;
          if (nxt != cur) {
            float* zp = z + (size_t)cur * 768 + t * 256 + n0 + cp * 2;
            unsafeAtomicAdd(zp, a0);
            unsafeAtomicAdd(zp + 1, a1);
            a0 = a1 = 0.f;
            cur = nxt;
          }
        }
      }
      bar_lds();  // hc reused next half / n0
    }
  }
}

// ---- out = elec + bf16(z) @ gT^T  (32x256 tiles, single-phase) -------------
// 256 blocks. A (32x768 f32 z-strip) staged ONCE to padded LDS; one barrier;
// all 24 K-steps barrier-free (B per-fragment from L2-resident gT).
__global__ __launch_bounds__(256) void k_final(const float* z, const u16* gT,
                                               const float* elec, float* out) {
  __shared__ __align__(16) char As[32 * ASTR_FN];  // 49664 B
  const int tid = threadIdx.x;
  const int m0 = blockIdx.x * 32;
  // stage A once: 32 rows x 768 f32 = 6144 float4, 24/thread, coalesced
#pragma unroll
  for (int i = 0; i < 24; ++i) {
    const int idx = i * 256 + tid;  // 0..6143
    const int row = idx / 192, q = idx % 192;
    const float4 v = *(const float4*)(z + (long)(m0 + row) * 768 + q * 4);
    uint2 p;
    p.x = pkbf(v.x, v.y);
    p.y = pkbf(v.z, v.w);
    *(uint2*)(As + row * ASTR_FN + q * 8) = p;
  }
  __syncthreads();
  const int l = tid & 63, lane15 = l & 15, quad = l >> 4, wv = tid >> 6;
  const int nw = wv * 64;
  f32x4 acc[2][4];
#pragma unroll
  for (int i = 0; i < 2; ++i)
#pragma unroll
    for (int j = 0; j < 4; ++j) acc[i][j] = (f32x4){0.f, 0.f, 0.f, 0.f};
  for (int kt = 0; kt < 768; kt += 32) {
    short8 af[2], bf[4];
#pragma unroll
    for (int i = 0; i < 2; ++i)
      af[i] = *(const short8*)(As + (i * 16 + lane15) * ASTR_FN + kt * 2 +
                               quad * 16);
#pragma unroll
    for (int i = 0; i < 4; ++i)
      bf[i] = *(const short8*)(gT + (nw + i * 16 + lane15) * 768 + kt +
                               quad * 8);
#pragma unroll
    for (int mi = 0; mi < 2; ++mi)
#pragma unroll
      for (int ni = 0; ni < 4; ++ni)
        acc[mi][ni] = __builtin_amdgcn_mfma_f32_16x16x32_bf16(
            af[mi], bf[ni], acc[mi][ni], 0, 0, 0);
  }
#pragma unroll
  for (int mi = 0; mi < 2; ++mi)
#pragma unroll
    for (int r = 0; r < 4; ++r) {
      const int row = m0 + mi * 16 + quad * 4 + r;
#pragma unroll
      for (int ni = 0; ni < 4; ++ni) {
        const int col = nw + ni * 16 + lane15;
        out[row * 256 + col] = acc[mi][ni][r] + elec[row * 256 + col];
      }
    }
}

// ---------------------------------------------------------------------------
extern "C" void kernel_launch(void* const* d_in, const int* in_sizes, int n_in,
                              void* d_out, int out_size, void* d_ws,
                              size_t ws_size, hipStream_t stream) {
  int I_dist[3], I_w1[3], I_b1[3], I_w2[3], I_g[3], I_hw;
  if (in_sizes[3] == 64 * 128) {  // setup_inputs() dict order
    for (int t = 0; t < 3; ++t) {
      I_dist[t] = 2 + t * 5 + 0;
      I_w1[t] = 2 + t * 5 + 1;
      I_b1[t] = 2 + t * 5 + 2;
      I_w2[t] = 2 + t * 5 + 3;
      I_g[t] = 2 + t * 5 + 4;
    }
    I_hw = 17;
  } else {  // reference signature order
    I_dist[0] = 2; I_dist[1] = 3; I_dist[2] = 4;
    I_w1[0] = 5;  I_b1[0] = 6;  I_w2[0] = 7;
    I_w1[1] = 8;  I_b1[1] = 9;  I_w2[1] = 10;
    I_w1[2] = 11; I_b1[2] = 12; I_w2[2] = 13;
    I_g[0] = 14; I_g[1] = 15; I_g[2] = 16;
    I_hw = 17;
  }
  const int I_snd[3] = {18, 19, 20};
  const int I_rcv[3] = {21, 22, 23};

  char* ws = (char*)d_ws;
  // workspace layout (bytes). Total ~34 MB.
  u16* he = (u16*)(ws + 0);              //   4,194,304
  u16* hwT = (u16*)(ws + 4194304);       //     131,072
  u16* w1T = (u16*)(ws + 4325376);       //      49,152
  u16* w2T = (u16*)(ws + 4374528);       //     196,608
  u16* gT = (u16*)(ws + 4571136);        //     393,216
  float* z = (float*)(ws + 4964352);     //  25,165,824
  int* cnt = (int*)(ws + 30130176);      //      98,304
  int* rowptr = (int*)(ws + 30228480);   //      99,072
  int* cursor = (int*)(ws + 30327552);   //      98,304
  u64* pk = (u64*)(ws + 30425856);       //   3,145,728

  const float* elec = (const float*)d_in[0];
  const float* nuc = (const float*)d_in[1];
  const int* s0 = (const int*)d_in[I_snd[0]];
  const int* s1 = (const int*)d_in[I_snd[1]];
  const int* s2 = (const int*)d_in[I_snd[2]];
  const int* r0 = (const int*)d_in[I_rcv[0]];
  const int* r1 = (const int*)d_in[I_rcv[1]];
  const int* r2 = (const int*)d_in[I_rcv[2]];

  // cnt = 0 (memset node; k_setup's histogram blocks atomically build on it)
  hipMemsetAsync(cnt, 0, 98304, stream);

  // z=0 (6144) + transposes (1504) + histogram (1536) in one dispatch
  k_setup<<<9184, 256, 0, stream>>>(
      (const float*)d_in[I_hw], (const float*)d_in[I_w1[0]],
      (const float*)d_in[I_w1[1]], (const float*)d_in[I_w1[2]],
      (const float*)d_in[I_w2[0]], (const float*)d_in[I_w2[1]],
      (const float*)d_in[I_w2[2]], (const float*)d_in[I_g[0]],
      (const float*)d_in[I_g[1]], (const float*)d_in[I_g[2]], r0, r1, r2,
      hwT, w1T, w2T, gT, (float4*)z, cnt);

  k_scan<<<3, 256, 0, stream>>>(cnt, rowptr, cursor);

  // place (1536 blocks) + he (256 blocks) in one dispatch
  k_place_he<<<1792, 256, 0, stream>>>(r0, r1, r2, s0, s1, s2, cursor, pk,
                                       elec, hwT, he);

  k_edge<<<dim3(NEDGE / 128, 1, 3), 256, 0, stream>>>(
      (const float*)d_in[I_dist[0]], (const float*)d_in[I_dist[1]],
      (const float*)d_in[I_dist[2]], (const float*)d_in[I_b1[0]],
      (const float*)d_in[I_b1[1]], (const float*)d_in[I_b1[2]], w1T, w2T, he,
      nuc, pk, z);

  k_final<<<N_ELEC / 32, 256, 0, stream>>>(z, gT, elec, (float*)d_out);
}